// Round 13
// baseline (177.396 us; speedup 1.0000x reference)
//
#include <hip/hip_runtime.h>
#include <math.h>

#define D 64
#define NB 64

typedef __attribute__((ext_vector_type(8))) short bf16x8;
typedef __attribute__((ext_vector_type(4))) float f32x4;
typedef __attribute__((ext_vector_type(16))) float f32x16;

#define M3(a, b, c) fmaxf(fmaxf((a), (b)), (c))

__device__ __forceinline__ unsigned short f2bf(float f) {
    unsigned u = __float_as_uint(f);
    u += 0x7FFF + ((u >> 16) & 1);
    return (unsigned short)(u >> 16);
}
__device__ __forceinline__ unsigned pk_bf16(float lo, float hi) {
    unsigned r;
    asm("v_cvt_pk_bf16_f32 %0, %1, %2" : "=v"(r) : "v"(lo), "v"(hi));
    return r;
}
__device__ __forceinline__ float fexp2(float x) {
    float r;
    asm("v_exp_f32 %0, %1" : "=v"(r) : "v"(x));
    return r;
}

// ---------------------------------------------------------------------------
// Prep: dst-degree histogram (both graphs) + batch start offsets (sorted ids)
// ---------------------------------------------------------------------------
__global__ void k_prep2(const int* __restrict__ em, int Em,
                        const int* __restrict__ ep, int Ep,
                        int* __restrict__ degm, int* __restrict__ degp,
                        const int* __restrict__ bm, int Nm, int* __restrict__ bsM,
                        const int* __restrict__ bp, int Np, int* __restrict__ bsP) {
    int i = blockIdx.x * blockDim.x + threadIdx.x;
    if (i < Em) atomicAdd(&degm[em[Em + i]], 1);
    int j = i - Em;
    if (j >= 0 && j < Ep) atomicAdd(&degp[ep[Ep + j]], 1);
    if (i < Nm) {
        int cur = bm[i];
        int prev = (i == 0) ? -1 : bm[i - 1];
        for (int b = prev + 1; b <= cur; ++b) bsM[b] = i;
        if (i == Nm - 1)
            for (int b = cur + 1; b <= NB; ++b) bsM[b] = Nm;
    }
    int j2 = i - Nm;
    if (j2 >= 0 && j2 < Np) {
        int cur = bp[j2];
        int prev = (j2 == 0) ? -1 : bp[j2 - 1];
        for (int b = prev + 1; b <= cur; ++b) bsP[b] = j2;
        if (j2 == Np - 1)
            for (int b = cur + 1; b <= NB; ++b) bsP[b] = Np;
    }
}

// ---------------------------------------------------------------------------
// CSR build: exclusive prefix sum (block 0 = mol, block 1 = prot)
// ---------------------------------------------------------------------------
__global__ __launch_bounds__(256) void k_scan2(
        const int* __restrict__ degm, int Nm, int* __restrict__ rpm, int* __restrict__ curm,
        const int* __restrict__ degp, int Np, int* __restrict__ rpp, int* __restrict__ curp) {
    __shared__ int sdeg[8192];
    __shared__ int chunk[256];
    const int* deg = blockIdx.x ? degp : degm;
    int N = blockIdx.x ? Np : Nm;
    int* rowptr = blockIdx.x ? rpp : rpm;
    int* cursor = blockIdx.x ? curp : curm;
    int t = threadIdx.x;
    for (int i = t; i < N; i += 256) sdeg[i] = deg[i];
    __syncthreads();
    int C = (N + 255) / 256;
    int start = t * C;
    int sum = 0;
    for (int i = 0; i < C; ++i)
        if (start + i < N) sum += sdeg[start + i];
    chunk[t] = sum;
    __syncthreads();
    for (int ofs = 1; ofs < 256; ofs <<= 1) {
        int v = (t >= ofs) ? chunk[t - ofs] : 0;
        __syncthreads();
        chunk[t] += v;
        __syncthreads();
    }
    int base = (t == 0) ? 0 : chunk[t - 1];
    for (int i = 0; i < C && start + i < N; ++i) {
        rowptr[start + i] = base;
        cursor[start + i] = base;
        base += sdeg[start + i];
    }
    if (t == 255) rowptr[N] = base;
}

// ---------------------------------------------------------------------------
// CSR build: scatter src indices (both graphs, one launch)
// ---------------------------------------------------------------------------
__global__ void k_scatter2(const int* __restrict__ em, int Em, int* __restrict__ curm,
                           int* __restrict__ csrm,
                           const int* __restrict__ ep, int Ep, int* __restrict__ curp,
                           int* __restrict__ csrp) {
    int i = blockIdx.x * blockDim.x + threadIdx.x;
    if (i < Em) {
        int s = em[i], d = em[Em + i];
        csrm[atomicAdd(&curm[d], 1)] = s;
    }
    int j = i - Em;
    if (j >= 0 && j < Ep) {
        int s = ep[j], d = ep[Ep + j];
        csrp[atomicAdd(&curp[d], 1)] = s;
    }
}

// ---------------------------------------------------------------------------
// Fused gather + SAGE linear body (one wave per row)
// ---------------------------------------------------------------------------
template<int FIN>
__device__ __forceinline__ void gsage_body(
        const float* __restrict__ x, const int* __restrict__ rowptr,
        const int* __restrict__ csr, int N,
        const float* __restrict__ wl, const float* __restrict__ bl,
        const float* __restrict__ wr, float* __restrict__ out,
        int blk, float* __restrict__ swl, float* __restrict__ swr,
        float* __restrict__ sagg, float* __restrict__ sx) {
    for (int i = threadIdx.x; i < FIN * D; i += 256) { swl[i] = wl[i]; swr[i] = wr[i]; }
    int w = threadIdx.x >> 6;
    int lane = threadIdx.x & 63;
    int r = blk * 4 + w;
    if (r < N) {
        int e0 = rowptr[r], e1 = rowptr[r + 1];
        float inv = 1.0f / fmaxf((float)(e1 - e0), 1.0f);
        if (FIN == 64) {
            float a0 = 0.f, a1 = 0.f, a2 = 0.f, a3 = 0.f;
            int e = e0;
            for (; e + 3 < e1; e += 4) {
                a0 += x[(size_t)csr[e] * FIN + lane];
                a1 += x[(size_t)csr[e + 1] * FIN + lane];
                a2 += x[(size_t)csr[e + 2] * FIN + lane];
                a3 += x[(size_t)csr[e + 3] * FIN + lane];
            }
            for (; e < e1; ++e) a0 += x[(size_t)csr[e] * FIN + lane];
            sagg[w * 64 + lane] = ((a0 + a1) + (a2 + a3)) * inv;
            sx[w * 64 + lane] = x[(size_t)r * FIN + lane];
        } else {
            int f = lane & 31, half = lane >> 5;
            float a = 0.f;
            for (int e = e0 + half; e < e1; e += 2)
                a += x[(size_t)csr[e] * FIN + f];
            a += __shfl_xor(a, 32);
            if (half == 0) {
                sagg[w * 64 + f] = a * inv;
                sx[w * 64 + f] = x[(size_t)r * FIN + f];
            }
        }
    }
    __syncthreads();
    if (r >= N) return;
    int c = lane;
    float acc = bl[c];
    #pragma unroll 8
    for (int k = 0; k < FIN; ++k) {
        acc += sagg[w * 64 + k] * swl[k * D + c];
        acc += sx[w * 64 + k] * swr[k * D + c];
    }
    out[(size_t)r * D + c] = fmaxf(acc, 0.0f);
}

template<int FA, int FB>
__global__ __launch_bounds__(256) void k_gsage2(
        const float* __restrict__ xA, const int* __restrict__ rpA,
        const int* __restrict__ csrA, int NA,
        const float* __restrict__ wlA, const float* __restrict__ blA,
        const float* __restrict__ wrA, float* __restrict__ outA,
        const float* __restrict__ xB, const int* __restrict__ rpB,
        const int* __restrict__ csrB, int NB_,
        const float* __restrict__ wlB, const float* __restrict__ blB,
        const float* __restrict__ wrB, float* __restrict__ outB) {
    __shared__ float swl[64 * 64];
    __shared__ float swr[64 * 64];
    __shared__ float sagg[4 * 64];
    __shared__ float sx[4 * 64];
    int bA = NA / 4;
    if ((int)blockIdx.x < bA)
        gsage_body<FA>(xA, rpA, csrA, NA, wlA, blA, wrA, outA, blockIdx.x, swl, swr, sagg, sx);
    else
        gsage_body<FB>(xB, rpB, csrB, NB_, wlB, blB, wrB, outB, blockIdx.x - bA, swl, swr, sagg, sx);
}

// ---------------------------------------------------------------------------
// Fused QKV projection -> bf16 (Q pre-scaled), both graphs in one launch.
// ---------------------------------------------------------------------------
__global__ __launch_bounds__(256) void k_qkv2(
        const float* __restrict__ xA, int NA, const float* __restrict__ xB, int NB_,
        const float* __restrict__ amp_w, const float* __restrict__ amp_b,
        const float* __restrict__ apm_w, const float* __restrict__ apm_b, float qs,
        unsigned short* __restrict__ QA, unsigned short* __restrict__ KA, unsigned short* __restrict__ VA,
        unsigned short* __restrict__ QB, unsigned short* __restrict__ KB, unsigned short* __restrict__ VB) {
    __shared__ float sq[D * D], sk[D * D], sv[D * D], sx[16 * D];
    int bA = NA / 16;
    const float *x, *wq, *bq, *wk, *bk, *wv, *bv;
    unsigned short *oq, *ok, *ov;
    int blk;
    if ((int)blockIdx.x < bA) {
        x = xA; blk = blockIdx.x;
        wq = amp_w;        bq = amp_b;
        wk = apm_w + 4096; bk = apm_b + 64;
        wv = apm_w + 8192; bv = apm_b + 128;
        oq = QA; ok = KA; ov = VA;
    } else {
        x = xB; blk = blockIdx.x - bA;
        wq = apm_w;        bq = apm_b;
        wk = amp_w + 4096; bk = amp_b + 64;
        wv = amp_w + 8192; bv = amp_b + 128;
        oq = QB; ok = KB; ov = VB;
    }
    for (int i = threadIdx.x; i < D * D; i += 256) { sq[i] = wq[i]; sk[i] = wk[i]; sv[i] = wv[i]; }
    int rbase = blk * 16;
    for (int i = threadIdx.x; i < 16 * D; i += 256) sx[i] = x[(size_t)rbase * D + i];
    __syncthreads();
    int c = threadIdx.x & 63;
    int r0 = (threadIdx.x >> 6) * 4;
    for (int rr = 0; rr < 4; ++rr) {
        int r = r0 + rr;
        float aq = bq[c], ak = bk[c], av = bv[c];
        #pragma unroll 8
        for (int k = 0; k < D; ++k) {
            float xv = sx[r * D + k];
            aq += xv * sq[k * D + c];
            ak += xv * sk[k * D + c];
            av += xv * sv[k * D + c];
        }
        size_t o = (size_t)(rbase + r) * D + c;
        oq[o] = f2bf(aq * qs);
        ok[o] = f2bf(ak);
        ov[o] = f2bf(av);
    }
}

// ---------------------------------------------------------------------------
// V transpose [N,64] -> [65,N] bf16 (row 64 = ones for the l-column trick),
// with within-32-chunk key permutation (swap bit2<->bit3) so the attn
// kernel's natural cvt_pk packing of scores IS the PV A-fragment.
// ---------------------------------------------------------------------------
__global__ void k_transp2(const unsigned short* __restrict__ inM, unsigned short* __restrict__ outM, int Nm,
                          const unsigned short* __restrict__ inP, unsigned short* __restrict__ outP, int Np) {
    __shared__ unsigned short tile[64][72];
    int bm = Nm >> 6;
    const unsigned short* in; unsigned short* out; int N;
    int blk = blockIdx.x;
    if (blk < bm) { in = inM; out = outM; N = Nm; }
    else { blk -= bm; in = inP; out = outP; N = Np; }
    int t = threadIdx.x;
    int rbase = blk * 64;
    {
        int r = t >> 2, c0 = (t & 3) * 16;
        const uint4* src = (const uint4*)(in + (size_t)(rbase + r) * 64 + c0);
        uint4 a = src[0], b = src[1];
        *(uint4*)(&tile[r][c0]) = a;
        *(uint4*)(&tile[r][c0 + 8]) = b;
    }
    __syncthreads();
    {
        int c = t >> 2, r0 = (t & 3) * 16;
        union { uint2 v2[4]; unsigned short s[16]; } u;
        #pragma unroll
        for (int i = 0; i < 16; ++i) u.s[i] = tile[r0 + i][c];
        int key0 = rbase + r0;
        int kc = key0 & ~31;
        int b16 = key0 & 16;
        unsigned short* op = out + (size_t)c * N;
        const int gmap[4] = {0, 8, 4, 12};
        #pragma unroll
        for (int b = 0; b < 4; ++b)
            *(uint2*)(op + kc + b16 + gmap[b]) = u.v2[b];
    }
    if (t < 8) {
        uint4 ones;
        ones.x = ones.y = ones.z = ones.w = 0x3F803F80u;  // bf16 1.0 pairs
        *(uint4*)(out + (size_t)64 * N + rbase + t * 8) = ones;
    }
}

// ---------------------------------------------------------------------------
// Split-K flash attention, 32x32x16 MFMA. 64 keys/iter (dual score tuples
// for ILP), dual independent O accumulators (halved PV chain depth),
// in-place exp2(s-m), NO setprio. l via ones-row col 16; permutation-free
// P->PV. Both directions one launch.
// ---------------------------------------------------------------------------
#define MAXTREE(cm, s0, s1)                                                   \
    {                                                                         \
        float c0 = M3(s0[0], s0[1], s0[2]);                                   \
        float c1 = M3(s0[3], s0[4], s0[5]);                                   \
        float c2 = M3(s0[6], s0[7], s0[8]);                                   \
        float c3 = M3(s0[9], s0[10], s0[11]);                                 \
        float c4 = M3(s0[12], s0[13], s0[14]);                                \
        float c5 = M3(s0[15], s1[0], s1[1]);                                  \
        float c6 = M3(s1[2], s1[3], s1[4]);                                   \
        float c7 = M3(s1[5], s1[6], s1[7]);                                   \
        float c8 = M3(s1[8], s1[9], s1[10]);                                  \
        float c9 = M3(s1[11], s1[12], s1[13]);                                \
        float ca = fmaxf(s1[14], s1[15]);                                     \
        float d0 = M3(c0, c1, c2);                                            \
        float d1 = M3(c3, c4, c5);                                            \
        float d2 = M3(c6, c7, c8);                                            \
        float d3 = M3(c9, ca, d0);                                            \
        cm = M3(d1, d2, d3);                                                  \
    }

#define PVPACK(S, KB, OA)                                                     \
    {                                                                         \
        union { unsigned u[4]; bf16x8 v; } f1, f2;                            \
        f1.u[0] = pk_bf16((S)[0], (S)[1]);   f1.u[1] = pk_bf16((S)[2], (S)[3]);  \
        f1.u[2] = pk_bf16((S)[4], (S)[5]);   f1.u[3] = pk_bf16((S)[6], (S)[7]);  \
        f2.u[0] = pk_bf16((S)[8], (S)[9]);   f2.u[1] = pk_bf16((S)[10], (S)[11]);\
        f2.u[2] = pk_bf16((S)[12], (S)[13]); f2.u[3] = pk_bf16((S)[14], (S)[15]);\
        bf16x8 vb0 = *(const bf16x8*)(vbase + (KB) + half * 8);               \
        bf16x8 vb1 = *(const bf16x8*)(vbase + (KB) + 16 + half * 8);          \
        OA = __builtin_amdgcn_mfma_f32_32x32x16_bf16(f1.v, vb0, OA, 0, 0, 0); \
        OA = __builtin_amdgcn_mfma_f32_32x32x16_bf16(f2.v, vb1, OA, 0, 0, 0); \
    }

__global__ __launch_bounds__(256) void k_attn4(
        const unsigned short* __restrict__ QmB, const unsigned short* __restrict__ KpB,
        const unsigned short* __restrict__ VpT, int Nm, int Np, int lsm,
        float* __restrict__ poM, float* __restrict__ pmM, float* __restrict__ plM,
        const unsigned short* __restrict__ QpB, const unsigned short* __restrict__ KmB,
        const unsigned short* __restrict__ VmT, int lsp,
        float* __restrict__ poP, float* __restrict__ pmP, float* __restrict__ plP) {
    const unsigned short *Q, *K, *Vt;
    int Nq, Nk, ls;
    float *po, *pm, *pl;
    if (blockIdx.y == 0) { Q = QmB; K = KpB; Vt = VpT; Nq = Nm; Nk = Np; ls = lsm; po = poM; pm = pmM; pl = plM; }
    else                 { Q = QpB; K = KmB; Vt = VmT; Nq = Np; Nk = Nm; ls = lsp; po = poP; pm = pmP; pl = plP; }
    int nqt = Nq >> 5;
    if ((int)blockIdx.x >= (nqt << ls)) return;
    const int qt = blockIdx.x >> ls;
    const int split = blockIdx.x & ((1 << ls) - 1);
    const int kchunk = Nk >> ls;       // multiple of 64
    const int h = threadIdx.x >> 6;
    const int lane = threadIdx.x & 63;
    const int cq = lane & 31;
    const int half = lane >> 5;
    const int h16 = h * 16;

    bf16x8 qb = *(const bf16x8*)(Q + ((size_t)(qt * 32 + cq) * D + h16 + half * 8));
    int drow = (cq < 16) ? (h16 + cq) : (cq == 16 ? 64 : h16 + 15);
    const unsigned short* vbase = Vt + (size_t)drow * Nk;

    f32x16 o0, o1, zro;
    #pragma unroll
    for (int i = 0; i < 16; ++i) { o0[i] = 0.f; o1[i] = 0.f; zro[i] = 0.f; }
    float m;

    const int kstart = split * kchunk;
    // ---- peeled first 64 keys ----
    {
        const int kb = kstart;
        bf16x8 ka0 = *(const bf16x8*)(K + ((size_t)(kb + cq) * D + h16 + half * 8));
        bf16x8 ka1 = *(const bf16x8*)(K + ((size_t)(kb + 32 + cq) * D + h16 + half * 8));
        f32x16 s0 = __builtin_amdgcn_mfma_f32_32x32x16_bf16(ka0, qb, zro, 0, 0, 0);
        f32x16 s1 = __builtin_amdgcn_mfma_f32_32x32x16_bf16(ka1, qb, zro, 0, 0, 0);
        float cm;
        MAXTREE(cm, s0, s1);
        #pragma unroll
        for (int off = 1; off < 64; off <<= 1) cm = fmaxf(cm, __shfl_xor(cm, off));
        m = cm;
        #pragma unroll
        for (int i = 0; i < 16; ++i) { s0[i] = fexp2(s0[i] - m); s1[i] = fexp2(s1[i] - m); }
        PVPACK(s0, kb, o0)
        PVPACK(s1, kb + 32, o1)
    }
    for (int kb = kstart + 64; kb < kstart + kchunk; kb += 64) {
        bf16x8 ka0 = *(const bf16x8*)(K + ((size_t)(kb + cq) * D + h16 + half * 8));
        bf16x8 ka1 = *(const bf16x8*)(K + ((size_t)(kb + 32 + cq) * D + h16 + half * 8));
        f32x16 s0 = __builtin_amdgcn_mfma_f32_32x32x16_bf16(ka0, qb, zro, 0, 0, 0);
        f32x16 s1 = __builtin_amdgcn_mfma_f32_32x32x16_bf16(ka1, qb, zro, 0, 0, 0);
        float cm;
        MAXTREE(cm, s0, s1);
        if (__any(cm > m + 8.f)) {        // deferred-max rescale (T13)
            float cw = cm;
            #pragma unroll
            for (int off = 1; off < 64; off <<= 1) cw = fmaxf(cw, __shfl_xor(cw, off));
            float nm = fmaxf(cw, m);
            float sc = fexp2(m - nm);
            #pragma unroll
            for (int i = 0; i < 16; ++i) { o0[i] *= sc; o1[i] *= sc; }
            m = nm;
        }
        #pragma unroll
        for (int i = 0; i < 16; ++i) { s0[i] = fexp2(s0[i] - m); s1[i] = fexp2(s1[i] - m); }
        PVPACK(s0, kb, o0)
        PVPACK(s1, kb + 32, o1)
    }

    f32x16 o;
    #pragma unroll
    for (int i = 0; i < 16; ++i) o[i] = o0[i] + o1[i];

    size_t pbase = (size_t)split * Nq + qt * 32;
    if (half == 0)
        pm[(pbase + cq) * 4 + h] = m;
    if (cq == 16) {
        #pragma unroll
        for (int r = 0; r < 16; ++r) {
            int qr = (r & 3) + 8 * (r >> 2) + 4 * half;
            pl[(pbase + qr) * 4 + h] = o[r];
        }
    }
    if (cq < 16) {
        #pragma unroll
        for (int r = 0; r < 16; ++r) {
            int qr = (r & 3) + 8 * (r >> 2) + 4 * half;
            po[(pbase + qr) * 64 + h16 + cq] = o[r];
        }
    }
}

// ---------------------------------------------------------------------------
// Combine split-K partials + residual -> dense h_c (plain float4 stores,
// NO atomics). Templated split count so the s-loop fully unrolls.
// ---------------------------------------------------------------------------
template<int NS>
__device__ __forceinline__ void comb_body(
        const float* __restrict__ po, const float* __restrict__ pm,
        const float* __restrict__ pl, int Nq,
        const float* __restrict__ resid, float* __restrict__ outc, int i) {
    int q = i >> 4;
    int part = i & 15;
    int d0 = part * 4;
    int h = part >> 2;
    float pmv[NS], plv[NS];
    #pragma unroll
    for (int s = 0; s < NS; ++s) pmv[s] = pm[((size_t)s * Nq + q) * 4 + h];
    #pragma unroll
    for (int s = 0; s < NS; ++s) plv[s] = pl[((size_t)s * Nq + q) * 4 + h];
    float M = pmv[0];
    #pragma unroll
    for (int s = 1; s < NS; ++s) M = fmaxf(M, pmv[s]);
    float4 O = {0.f, 0.f, 0.f, 0.f};
    float L = 0.f;
    #pragma unroll
    for (int s = 0; s < NS; ++s) {
        float wgt = fexp2(pmv[s] - M);
        float4 pv = *(const float4*)(po + ((size_t)s * Nq + q) * 64 + d0);
        O.x += pv.x * wgt; O.y += pv.y * wgt; O.z += pv.z * wgt; O.w += pv.w * wgt;
        L += plv[s] * wgt;
    }
    float invL = 1.0f / L;
    float4 rv = *(const float4*)(resid + (size_t)q * 64 + d0);
    float4 res;
    res.x = rv.x + O.x * invL;
    res.y = rv.y + O.y * invL;
    res.z = rv.z + O.z * invL;
    res.w = rv.w + O.w * invL;
    *(float4*)(outc + (size_t)q * 64 + d0) = res;
}

template<int NSM, int NSP>
__global__ void k_comb2t(
        const float* __restrict__ poM, const float* __restrict__ pmM, const float* __restrict__ plM,
        int Nm, const float* __restrict__ residM, float* __restrict__ outM,
        const float* __restrict__ poP, const float* __restrict__ pmP, const float* __restrict__ plP,
        int Np, const float* __restrict__ residP, float* __restrict__ outP) {
    int idx = blockIdx.x * blockDim.x + threadIdx.x;
    int mtot = Nm * 16;
    if (idx < mtot)
        comb_body<NSM>(poM, pmM, plM, Nm, residM, outM, idx);
    else if (idx - mtot < Np * 16)
        comb_body<NSP>(poP, pmP, plP, Np, residP, outP, idx - mtot);
}

// Generic fallback (runtime ns, scalar path)
__global__ void k_comb2(
        const float* __restrict__ poM, const float* __restrict__ pmM, const float* __restrict__ plM,
        int nsM, int Nm, const float* __restrict__ residM, float* __restrict__ outM,
        const float* __restrict__ poP, const float* __restrict__ pmP, const float* __restrict__ plP,
        int nsP, int Np, const float* __restrict__ residP, float* __restrict__ outP) {
    int idx = blockIdx.x * blockDim.x + threadIdx.x;
    const float *po, *pm, *pl, *resid;
    float* outc;
    int ns, Nq, i;
    int mtot = Nm * 64;
    if (idx < mtot) {
        po = poM; pm = pmM; pl = plM; ns = nsM; Nq = Nm; resid = residM; outc = outM; i = idx;
    } else {
        i = idx - mtot;
        if (i >= Np * 64) return;
        po = poP; pm = pmP; pl = plP; ns = nsP; Nq = Np; resid = residP; outc = outP;
    }
    int q = i >> 6, d = i & 63, h = d >> 4;
    float M = -1e30f;
    for (int s = 0; s < ns; ++s)
        M = fmaxf(M, pm[((size_t)s * Nq + q) * 4 + h]);
    float O = 0.f, L = 0.f;
    for (int s = 0; s < ns; ++s) {
        float wgt = fexp2(pm[((size_t)s * Nq + q) * 4 + h] - M);
        O += po[((size_t)s * Nq + q) * 64 + d] * wgt;
        L += pl[((size_t)s * Nq + q) * 4 + h] * wgt;
    }
    outc[i] = resid[i] + O / L;
}

// ---------------------------------------------------------------------------
// Per-batch pooling over sorted batch ranges: one block per (batch, graph).
// Direct stores, zero atomics.
// ---------------------------------------------------------------------------
__global__ __launch_bounds__(256) void k_pool2(
        const float* __restrict__ hM, const int* __restrict__ bsM,
        const float* __restrict__ hP, const int* __restrict__ bsP,
        float* __restrict__ zsum, float* __restrict__ zcnt) {
    __shared__ float red[4][64];
    int b = blockIdx.x & 63;
    int isP = blockIdx.x >> 6;
    const float* h = isP ? hP : hM;
    const int* bs = isP ? bsP : bsM;
    int colOff = isP ? 64 : 0;
    int n0 = bs[b], n1 = bs[b + 1];
    int w = threadIdx.x >> 6, c = threadIdx.x & 63;
    float acc = 0.f;
    for (int n = n0 + w; n < n1; n += 4)
        acc += h[(size_t)n * 64 + c];
    red[w][c] = acc;
    __syncthreads();
    if (w == 0) {
        float s = (red[0][c] + red[1][c]) + (red[2][c] + red[3][c]);
        zsum[b * 128 + colOff + c] = s;
        if (c == 0) zcnt[b * 2 + isP] = (float)(n1 - n0);
    }
}

// ---------------------------------------------------------------------------
// Head MLP: one wave per batch element
// ---------------------------------------------------------------------------
__global__ __launch_bounds__(256) void k_head2(
        const float* __restrict__ zsum, const float* __restrict__ zcnt,
        const float* __restrict__ fc1w, const float* __restrict__ fc1b,
        const float* __restrict__ fc2w, const float* __restrict__ fc2b,
        float* __restrict__ out) {
    int b = blockIdx.x * 4 + (threadIdx.x >> 6);
    int c = threadIdx.x & 63;
    float inv0 = 1.0f / fmaxf(zcnt[b * 2 + 0], 1.0f);
    float inv1 = 1.0f / fmaxf(zcnt[b * 2 + 1], 1.0f);
    float acc = fc1b[c];
    #pragma unroll 8
    for (int k = 0; k < 128; ++k) {
        float zv = zsum[b * 128 + k] * (k < 64 ? inv0 : inv1);
        acc += zv * fc1w[k * 64 + c];
    }
    float v = fmaxf(acc, 0.0f) * fc2w[c];
    #pragma unroll
    for (int off = 32; off > 0; off >>= 1) v += __shfl_xor(v, off);
    if (c == 0) out[b] = 1.0f / (1.0f + __expf(-(v + fc2b[0])));
}

// ---------------------------------------------------------------------------
extern "C" void kernel_launch(void* const* d_in, const int* in_sizes, int n_in,
                              void* d_out, int out_size, void* d_ws, size_t ws_size,
                              hipStream_t stream) {
    const float* x_mol  = (const float*)d_in[0];
    const float* x_prot = (const float*)d_in[1];
    const float* m1_wl = (const float*)d_in[2];
    const float* m1_bl = (const float*)d_in[3];
    const float* m1_wr = (const float*)d_in[4];
    const float* m2_wl = (const float*)d_in[5];
    const float* m2_bl = (const float*)d_in[6];
    const float* m2_wr = (const float*)d_in[7];
    const float* p1_wl = (const float*)d_in[8];
    const float* p1_bl = (const float*)d_in[9];
    const float* p1_wr = (const float*)d_in[10];
    const float* p2_wl = (const float*)d_in[11];
    const float* p2_bl = (const float*)d_in[12];
    const float* p2_wr = (const float*)d_in[13];
    const float* amp_w = (const float*)d_in[14];
    const float* amp_b = (const float*)d_in[15];
    const float* apm_w = (const float*)d_in[16];
    const float* apm_b = (const float*)d_in[17];
    const float* fc1_w = (const float*)d_in[18];
    const float* fc1_b = (const float*)d_in[19];
    const float* fc2_w = (const float*)d_in[20];
    const float* fc2_b = (const float*)d_in[21];
    const int* edge_mol  = (const int*)d_in[22];
    const int* edge_prot = (const int*)d_in[23];
    const int* batch_mol  = (const int*)d_in[24];
    const int* batch_prot = (const int*)d_in[25];
    float* out = (float*)d_out;

    const int N_MOL  = in_sizes[0] / 32;
    const int N_PROT = in_sizes[1] / 64;
    const int E_MOL  = in_sizes[22] / 2;
    const int E_PROT = in_sizes[23] / 2;

    // ---- workspace bump allocator ----
    char* base = (char*)d_ws;
    size_t off = 0;
    auto alloc = [&](size_t bytes) -> void* {
        void* p = base + off;
        off = (off + bytes + 255) & ~(size_t)255;
        return p;
    };
    float* h_mol1   = (float*)alloc((size_t)N_MOL * D * sizeof(float));
    float* h_mol2   = (float*)alloc((size_t)N_MOL * D * sizeof(float));
    float* h_prot1  = (float*)alloc((size_t)N_PROT * D * sizeof(float));
    float* h_prot2  = (float*)alloc((size_t)N_PROT * D * sizeof(float));
    float* h_mol_c  = (float*)alloc((size_t)N_MOL * D * sizeof(float));
    float* h_prot_c = (float*)alloc((size_t)N_PROT * D * sizeof(float));
    float* zsum     = (float*)alloc((NB * 128 + NB * 2) * sizeof(float));
    float* zcnt     = zsum + NB * 128;
    unsigned short* Qm_b = (unsigned short*)alloc((size_t)N_MOL * D * 2);
    unsigned short* Km_b = (unsigned short*)alloc((size_t)N_MOL * D * 2);
    unsigned short* Vm_b = (unsigned short*)alloc((size_t)N_MOL * D * 2);
    unsigned short* Vm_t = (unsigned short*)alloc((size_t)N_MOL * (D + 1) * 2);
    unsigned short* Qp_b = (unsigned short*)alloc((size_t)N_PROT * D * 2);
    unsigned short* Kp_b = (unsigned short*)alloc((size_t)N_PROT * D * 2);
    unsigned short* Vp_b = (unsigned short*)alloc((size_t)N_PROT * D * 2);
    unsigned short* Vp_t = (unsigned short*)alloc((size_t)N_PROT * (D + 1) * 2);
    // CSR
    int* deg      = (int*)alloc(((size_t)N_MOL + N_PROT) * sizeof(int));
    int* deg_m    = deg;
    int* deg_p    = deg + N_MOL;
    int* rp_m     = (int*)alloc(((size_t)N_MOL + 1) * sizeof(int));
    int* cur_m    = (int*)alloc((size_t)N_MOL * sizeof(int));
    int* csr_m    = (int*)alloc((size_t)E_MOL * sizeof(int));
    int* rp_p     = (int*)alloc(((size_t)N_PROT + 1) * sizeof(int));
    int* cur_p    = (int*)alloc((size_t)N_PROT * sizeof(int));
    int* csr_p    = (int*)alloc((size_t)E_PROT * sizeof(int));
    int* bsM      = (int*)alloc((NB + 1) * sizeof(int));
    int* bsP      = (int*)alloc((NB + 1) * sizeof(int));

    // split-K factors (keys per split must be a multiple of 64)
    int nsm = 16; while (nsm > 1 && (N_PROT % (64 * nsm))) nsm >>= 1;  // mol queries prot keys
    int nsp = 4;  while (nsp > 1 && (N_MOL % (64 * nsp)))  nsp >>= 1;  // prot queries mol keys
    int lsm = 31 - __builtin_clz(nsm);
    int lsp = 31 - __builtin_clz(nsp);
    float* poM = (float*)alloc((size_t)nsm * N_MOL * 64 * sizeof(float));
    float* pmM = (float*)alloc((size_t)nsm * N_MOL * 4 * sizeof(float));
    float* plM = (float*)alloc((size_t)nsm * N_MOL * 4 * sizeof(float));
    float* poP = (float*)alloc((size_t)nsp * N_PROT * 64 * sizeof(float));
    float* pmP = (float*)alloc((size_t)nsp * N_PROT * 4 * sizeof(float));
    float* plP = (float*)alloc((size_t)nsp * N_PROT * 4 * sizeof(float));

    const int BLK = 256;
    dim3 blk(BLK);
    const float QS = 0.25f * 1.4426950408889634f;  // 1/sqrt(DH) * log2(e)

    // ---- CSR build + batch starts ----
    hipMemsetAsync(deg, 0, ((size_t)N_MOL + N_PROT) * sizeof(int), stream);
    int Etot = E_MOL + E_PROT;
    k_prep2<<<(Etot + BLK - 1) / BLK, blk, 0, stream>>>(
        edge_mol, E_MOL, edge_prot, E_PROT, deg_m, deg_p,
        batch_mol, N_MOL, bsM, batch_prot, N_PROT, bsP);
    k_scan2<<<2, blk, 0, stream>>>(deg_m, N_MOL, rp_m, cur_m, deg_p, N_PROT, rp_p, cur_p);
    k_scatter2<<<(Etot + BLK - 1) / BLK, blk, 0, stream>>>(edge_mol, E_MOL, cur_m, csr_m,
                                                           edge_prot, E_PROT, cur_p, csr_p);

    // ---- SAGE layers (mol + prot merged per layer) ----
    k_gsage2<32, 64><<<N_MOL / 4 + N_PROT / 4, blk, 0, stream>>>(
        x_mol,  rp_m, csr_m, N_MOL,  m1_wl, m1_bl, m1_wr, h_mol1,
        x_prot, rp_p, csr_p, N_PROT, p1_wl, p1_bl, p1_wr, h_prot1);
    k_gsage2<64, 64><<<N_MOL / 4 + N_PROT / 4, blk, 0, stream>>>(
        h_mol1,  rp_m, csr_m, N_MOL,  m2_wl, m2_bl, m2_wr, h_mol2,
        h_prot1, rp_p, csr_p, N_PROT, p2_wl, p2_bl, p2_wr, h_prot2);

    // ---- QKV projections (merged) ----
    k_qkv2<<<N_MOL / 16 + N_PROT / 16, blk, 0, stream>>>(
        h_mol2, N_MOL, h_prot2, N_PROT, amp_w, amp_b, apm_w, apm_b, QS,
        Qm_b, Km_b, Vm_b, Qp_b, Kp_b, Vp_b);

    // ---- V transposes (merged, permuted, + ones row) ----
    k_transp2<<<N_MOL / 64 + N_PROT / 64, blk, 0, stream>>>(Vm_b, Vm_t, N_MOL, Vp_b, Vp_t, N_PROT);

    // ---- split-K flash attention (both directions, one launch) ----
    int gxm = (N_MOL / 32) * nsm;
    int gxp = (N_PROT / 32) * nsp;
    int gx = gxm > gxp ? gxm : gxp;
    k_attn4<<<dim3(gx, 2), blk, 0, stream>>>(
        Qm_b, Kp_b, Vp_t, N_MOL, N_PROT, lsm, poM, pmM, plM,
        Qp_b, Km_b, Vm_t, lsp, poP, pmP, plP);

    // ---- combine + residual -> h_c (no atomics) ----
    if (nsm == 16 && nsp == 4) {
        int tot = (N_MOL + N_PROT) * 16;
        k_comb2t<16, 4><<<(tot + BLK - 1) / BLK, blk, 0, stream>>>(
            poM, pmM, plM, N_MOL, h_mol2, h_mol_c,
            poP, pmP, plP, N_PROT, h_prot2, h_prot_c);
    } else {
        k_comb2<<<((N_MOL + N_PROT) * 64 + BLK - 1) / BLK, blk, 0, stream>>>(
            poM, pmM, plM, nsm, N_MOL, h_mol2, h_mol_c,
            poP, pmP, plP, nsp, N_PROT, h_prot2, h_prot_c);
    }

    // ---- per-batch pooling (no atomics) ----
    k_pool2<<<128, blk, 0, stream>>>(h_mol_c, bsM, h_prot_c, bsP, zsum, zcnt);

    // ---- head ----
    k_head2<<<16, blk, 0, stream>>>(zsum, zcnt, fc1_w, fc1_b, fc2_w, fc2_b, out);
}

// Round 14
// 174.258 us; speedup vs baseline: 1.0180x; 1.0180x over previous
//
#include <hip/hip_runtime.h>
#include <math.h>

#define D 64
#define NB 64

typedef __attribute__((ext_vector_type(8))) short bf16x8;
typedef __attribute__((ext_vector_type(4))) float f32x4;
typedef __attribute__((ext_vector_type(16))) float f32x16;

#define M3(a, b, c) fmaxf(fmaxf((a), (b)), (c))

__device__ __forceinline__ unsigned short f2bf(float f) {
    unsigned u = __float_as_uint(f);
    u += 0x7FFF + ((u >> 16) & 1);
    return (unsigned short)(u >> 16);
}
__device__ __forceinline__ unsigned pk_bf16(float lo, float hi) {
    unsigned r;
    asm("v_cvt_pk_bf16_f32 %0, %1, %2" : "=v"(r) : "v"(lo), "v"(hi));
    return r;
}
__device__ __forceinline__ float fexp2(float x) {
    float r;
    asm("v_exp_f32 %0, %1" : "=v"(r) : "v"(x));
    return r;
}

// ---------------------------------------------------------------------------
// Prep: dst-degree histogram (both graphs) + batch start offsets (sorted ids)
// ---------------------------------------------------------------------------
__global__ void k_prep2(const int* __restrict__ em, int Em,
                        const int* __restrict__ ep, int Ep,
                        int* __restrict__ degm, int* __restrict__ degp,
                        const int* __restrict__ bm, int Nm, int* __restrict__ bsM,
                        const int* __restrict__ bp, int Np, int* __restrict__ bsP) {
    int i = blockIdx.x * blockDim.x + threadIdx.x;
    if (i < Em) atomicAdd(&degm[em[Em + i]], 1);
    int j = i - Em;
    if (j >= 0 && j < Ep) atomicAdd(&degp[ep[Ep + j]], 1);
    if (i < Nm) {
        int cur = bm[i];
        int prev = (i == 0) ? -1 : bm[i - 1];
        for (int b = prev + 1; b <= cur; ++b) bsM[b] = i;
        if (i == Nm - 1)
            for (int b = cur + 1; b <= NB; ++b) bsM[b] = Nm;
    }
    int j2 = i - Nm;
    if (j2 >= 0 && j2 < Np) {
        int cur = bp[j2];
        int prev = (j2 == 0) ? -1 : bp[j2 - 1];
        for (int b = prev + 1; b <= cur; ++b) bsP[b] = j2;
        if (j2 == Np - 1)
            for (int b = cur + 1; b <= NB; ++b) bsP[b] = Np;
    }
}

// ---------------------------------------------------------------------------
// CSR build: exclusive prefix sum (block 0 = mol, block 1 = prot)
// ---------------------------------------------------------------------------
__global__ __launch_bounds__(256) void k_scan2(
        const int* __restrict__ degm, int Nm, int* __restrict__ rpm, int* __restrict__ curm,
        const int* __restrict__ degp, int Np, int* __restrict__ rpp, int* __restrict__ curp) {
    __shared__ int sdeg[8192];
    __shared__ int chunk[256];
    const int* deg = blockIdx.x ? degp : degm;
    int N = blockIdx.x ? Np : Nm;
    int* rowptr = blockIdx.x ? rpp : rpm;
    int* cursor = blockIdx.x ? curp : curm;
    int t = threadIdx.x;
    for (int i = t; i < N; i += 256) sdeg[i] = deg[i];
    __syncthreads();
    int C = (N + 255) / 256;
    int start = t * C;
    int sum = 0;
    for (int i = 0; i < C; ++i)
        if (start + i < N) sum += sdeg[start + i];
    chunk[t] = sum;
    __syncthreads();
    for (int ofs = 1; ofs < 256; ofs <<= 1) {
        int v = (t >= ofs) ? chunk[t - ofs] : 0;
        __syncthreads();
        chunk[t] += v;
        __syncthreads();
    }
    int base = (t == 0) ? 0 : chunk[t - 1];
    for (int i = 0; i < C && start + i < N; ++i) {
        rowptr[start + i] = base;
        cursor[start + i] = base;
        base += sdeg[start + i];
    }
    if (t == 255) rowptr[N] = base;
}

// ---------------------------------------------------------------------------
// CSR build: scatter src indices (both graphs, one launch)
// ---------------------------------------------------------------------------
__global__ void k_scatter2(const int* __restrict__ em, int Em, int* __restrict__ curm,
                           int* __restrict__ csrm,
                           const int* __restrict__ ep, int Ep, int* __restrict__ curp,
                           int* __restrict__ csrp) {
    int i = blockIdx.x * blockDim.x + threadIdx.x;
    if (i < Em) {
        int s = em[i], d = em[Em + i];
        csrm[atomicAdd(&curm[d], 1)] = s;
    }
    int j = i - Em;
    if (j >= 0 && j < Ep) {
        int s = ep[j], d = ep[Ep + j];
        csrp[atomicAdd(&curp[d], 1)] = s;
    }
}

// ---------------------------------------------------------------------------
// Fused gather + SAGE linear body (one wave per row)
// ---------------------------------------------------------------------------
template<int FIN>
__device__ __forceinline__ void gsage_body(
        const float* __restrict__ x, const int* __restrict__ rowptr,
        const int* __restrict__ csr, int N,
        const float* __restrict__ wl, const float* __restrict__ bl,
        const float* __restrict__ wr, float* __restrict__ out,
        int blk, float* __restrict__ swl, float* __restrict__ swr,
        float* __restrict__ sagg, float* __restrict__ sx) {
    for (int i = threadIdx.x; i < FIN * D; i += 256) { swl[i] = wl[i]; swr[i] = wr[i]; }
    int w = threadIdx.x >> 6;
    int lane = threadIdx.x & 63;
    int r = blk * 4 + w;
    if (r < N) {
        int e0 = rowptr[r], e1 = rowptr[r + 1];
        float inv = 1.0f / fmaxf((float)(e1 - e0), 1.0f);
        if (FIN == 64) {
            float a0 = 0.f, a1 = 0.f, a2 = 0.f, a3 = 0.f;
            int e = e0;
            for (; e + 3 < e1; e += 4) {
                a0 += x[(size_t)csr[e] * FIN + lane];
                a1 += x[(size_t)csr[e + 1] * FIN + lane];
                a2 += x[(size_t)csr[e + 2] * FIN + lane];
                a3 += x[(size_t)csr[e + 3] * FIN + lane];
            }
            for (; e < e1; ++e) a0 += x[(size_t)csr[e] * FIN + lane];
            sagg[w * 64 + lane] = ((a0 + a1) + (a2 + a3)) * inv;
            sx[w * 64 + lane] = x[(size_t)r * FIN + lane];
        } else {
            int f = lane & 31, half = lane >> 5;
            float a = 0.f;
            for (int e = e0 + half; e < e1; e += 2)
                a += x[(size_t)csr[e] * FIN + f];
            a += __shfl_xor(a, 32);
            if (half == 0) {
                sagg[w * 64 + f] = a * inv;
                sx[w * 64 + f] = x[(size_t)r * FIN + f];
            }
        }
    }
    __syncthreads();
    if (r >= N) return;
    int c = lane;
    float acc = bl[c];
    #pragma unroll 8
    for (int k = 0; k < FIN; ++k) {
        acc += sagg[w * 64 + k] * swl[k * D + c];
        acc += sx[w * 64 + k] * swr[k * D + c];
    }
    out[(size_t)r * D + c] = fmaxf(acc, 0.0f);
}

template<int FA, int FB>
__global__ __launch_bounds__(256) void k_gsage2(
        const float* __restrict__ xA, const int* __restrict__ rpA,
        const int* __restrict__ csrA, int NA,
        const float* __restrict__ wlA, const float* __restrict__ blA,
        const float* __restrict__ wrA, float* __restrict__ outA,
        const float* __restrict__ xB, const int* __restrict__ rpB,
        const int* __restrict__ csrB, int NB_,
        const float* __restrict__ wlB, const float* __restrict__ blB,
        const float* __restrict__ wrB, float* __restrict__ outB) {
    __shared__ float swl[64 * 64];
    __shared__ float swr[64 * 64];
    __shared__ float sagg[4 * 64];
    __shared__ float sx[4 * 64];
    int bA = NA / 4;
    if ((int)blockIdx.x < bA)
        gsage_body<FA>(xA, rpA, csrA, NA, wlA, blA, wrA, outA, blockIdx.x, swl, swr, sagg, sx);
    else
        gsage_body<FB>(xB, rpB, csrB, NB_, wlB, blB, wrB, outB, blockIdx.x - bA, swl, swr, sagg, sx);
}

// ---------------------------------------------------------------------------
// Fused QKV projection -> bf16 (Q pre-scaled), both graphs in one launch.
// ---------------------------------------------------------------------------
__global__ __launch_bounds__(256) void k_qkv2(
        const float* __restrict__ xA, int NA, const float* __restrict__ xB, int NB_,
        const float* __restrict__ amp_w, const float* __restrict__ amp_b,
        const float* __restrict__ apm_w, const float* __restrict__ apm_b, float qs,
        unsigned short* __restrict__ QA, unsigned short* __restrict__ KA, unsigned short* __restrict__ VA,
        unsigned short* __restrict__ QB, unsigned short* __restrict__ KB, unsigned short* __restrict__ VB) {
    __shared__ float sq[D * D], sk[D * D], sv[D * D], sx[16 * D];
    int bA = NA / 16;
    const float *x, *wq, *bq, *wk, *bk, *wv, *bv;
    unsigned short *oq, *ok, *ov;
    int blk;
    if ((int)blockIdx.x < bA) {
        x = xA; blk = blockIdx.x;
        wq = amp_w;        bq = amp_b;
        wk = apm_w + 4096; bk = apm_b + 64;
        wv = apm_w + 8192; bv = apm_b + 128;
        oq = QA; ok = KA; ov = VA;
    } else {
        x = xB; blk = blockIdx.x - bA;
        wq = apm_w;        bq = apm_b;
        wk = amp_w + 4096; bk = amp_b + 64;
        wv = amp_w + 8192; bv = amp_b + 128;
        oq = QB; ok = KB; ov = VB;
    }
    for (int i = threadIdx.x; i < D * D; i += 256) { sq[i] = wq[i]; sk[i] = wk[i]; sv[i] = wv[i]; }
    int rbase = blk * 16;
    for (int i = threadIdx.x; i < 16 * D; i += 256) sx[i] = x[(size_t)rbase * D + i];
    __syncthreads();
    int c = threadIdx.x & 63;
    int r0 = (threadIdx.x >> 6) * 4;
    for (int rr = 0; rr < 4; ++rr) {
        int r = r0 + rr;
        float aq = bq[c], ak = bk[c], av = bv[c];
        #pragma unroll 8
        for (int k = 0; k < D; ++k) {
            float xv = sx[r * D + k];
            aq += xv * sq[k * D + c];
            ak += xv * sk[k * D + c];
            av += xv * sv[k * D + c];
        }
        size_t o = (size_t)(rbase + r) * D + c;
        oq[o] = f2bf(aq * qs);
        ok[o] = f2bf(ak);
        ov[o] = f2bf(av);
    }
}

// ---------------------------------------------------------------------------
// V transpose [N,64] -> [65,N] bf16 (row 64 = ones for the l-column trick),
// with within-32-chunk key permutation (swap bit2<->bit3) so the attn
// kernel's natural cvt_pk packing of scores IS the PV A-fragment.
// ---------------------------------------------------------------------------
__global__ void k_transp2(const unsigned short* __restrict__ inM, unsigned short* __restrict__ outM, int Nm,
                          const unsigned short* __restrict__ inP, unsigned short* __restrict__ outP, int Np) {
    __shared__ unsigned short tile[64][72];
    int bm = Nm >> 6;
    const unsigned short* in; unsigned short* out; int N;
    int blk = blockIdx.x;
    if (blk < bm) { in = inM; out = outM; N = Nm; }
    else { blk -= bm; in = inP; out = outP; N = Np; }
    int t = threadIdx.x;
    int rbase = blk * 64;
    {
        int r = t >> 2, c0 = (t & 3) * 16;
        const uint4* src = (const uint4*)(in + (size_t)(rbase + r) * 64 + c0);
        uint4 a = src[0], b = src[1];
        *(uint4*)(&tile[r][c0]) = a;
        *(uint4*)(&tile[r][c0 + 8]) = b;
    }
    __syncthreads();
    {
        int c = t >> 2, r0 = (t & 3) * 16;
        union { uint2 v2[4]; unsigned short s[16]; } u;
        #pragma unroll
        for (int i = 0; i < 16; ++i) u.s[i] = tile[r0 + i][c];
        int key0 = rbase + r0;
        int kc = key0 & ~31;
        int b16 = key0 & 16;
        unsigned short* op = out + (size_t)c * N;
        const int gmap[4] = {0, 8, 4, 12};
        #pragma unroll
        for (int b = 0; b < 4; ++b)
            *(uint2*)(op + kc + b16 + gmap[b]) = u.v2[b];
    }
    if (t < 8) {
        uint4 ones;
        ones.x = ones.y = ones.z = ones.w = 0x3F803F80u;  // bf16 1.0 pairs
        *(uint4*)(out + (size_t)64 * N + rbase + t * 8) = ones;
    }
}

// ---------------------------------------------------------------------------
// Split-K flash attention, 32x32x16 MFMA — BRANCHLESS steady loop.
// m = first-64-key max (fixed per split; rescale factors cancel exactly in
// the O/L division at combine time, so no running-max updates are needed).
// Steady loop: s = mfma(K, Q, -m) -> exp2 in place -> pack -> PV. No
// maxtree, no __any, no rescale => compiler can software-pipeline loads.
// l via ones-row col 16; permutation-free P->PV. Both directions one launch.
// ---------------------------------------------------------------------------
#define MAXTREE(cm, s0, s1)                                                   \
    {                                                                         \
        float c0 = M3(s0[0], s0[1], s0[2]);                                   \
        float c1 = M3(s0[3], s0[4], s0[5]);                                   \
        float c2 = M3(s0[6], s0[7], s0[8]);                                   \
        float c3 = M3(s0[9], s0[10], s0[11]);                                 \
        float c4 = M3(s0[12], s0[13], s0[14]);                                \
        float c5 = M3(s0[15], s1[0], s1[1]);                                  \
        float c6 = M3(s1[2], s1[3], s1[4]);                                   \
        float c7 = M3(s1[5], s1[6], s1[7]);                                   \
        float c8 = M3(s1[8], s1[9], s1[10]);                                  \
        float c9 = M3(s1[11], s1[12], s1[13]);                                \
        float ca = fmaxf(s1[14], s1[15]);                                     \
        float d0 = M3(c0, c1, c2);                                            \
        float d1 = M3(c3, c4, c5);                                            \
        float d2 = M3(c6, c7, c8);                                            \
        float d3 = M3(c9, ca, d0);                                            \
        cm = M3(d1, d2, d3);                                                  \
    }

#define PVPACK(S, KB)                                                         \
    {                                                                         \
        union { unsigned u[4]; bf16x8 v; } f1, f2;                            \
        f1.u[0] = pk_bf16((S)[0], (S)[1]);   f1.u[1] = pk_bf16((S)[2], (S)[3]);  \
        f1.u[2] = pk_bf16((S)[4], (S)[5]);   f1.u[3] = pk_bf16((S)[6], (S)[7]);  \
        f2.u[0] = pk_bf16((S)[8], (S)[9]);   f2.u[1] = pk_bf16((S)[10], (S)[11]);\
        f2.u[2] = pk_bf16((S)[12], (S)[13]); f2.u[3] = pk_bf16((S)[14], (S)[15]);\
        bf16x8 vb0 = *(const bf16x8*)(vbase + (KB) + half * 8);               \
        bf16x8 vb1 = *(const bf16x8*)(vbase + (KB) + 16 + half * 8);          \
        __builtin_amdgcn_s_setprio(1);                                        \
        o = __builtin_amdgcn_mfma_f32_32x32x16_bf16(f1.v, vb0, o, 0, 0, 0);   \
        o = __builtin_amdgcn_mfma_f32_32x32x16_bf16(f2.v, vb1, o, 0, 0, 0);   \
        __builtin_amdgcn_s_setprio(0);                                        \
    }

__global__ __launch_bounds__(256) void k_attn5(
        const unsigned short* __restrict__ QmB, const unsigned short* __restrict__ KpB,
        const unsigned short* __restrict__ VpT, int Nm, int Np, int lsm,
        float* __restrict__ poM, float* __restrict__ pmM, float* __restrict__ plM,
        const unsigned short* __restrict__ QpB, const unsigned short* __restrict__ KmB,
        const unsigned short* __restrict__ VmT, int lsp,
        float* __restrict__ poP, float* __restrict__ pmP, float* __restrict__ plP) {
    const unsigned short *Q, *K, *Vt;
    int Nq, Nk, ls;
    float *po, *pm, *pl;
    if (blockIdx.y == 0) { Q = QmB; K = KpB; Vt = VpT; Nq = Nm; Nk = Np; ls = lsm; po = poM; pm = pmM; pl = plM; }
    else                 { Q = QpB; K = KmB; Vt = VmT; Nq = Np; Nk = Nm; ls = lsp; po = poP; pm = pmP; pl = plP; }
    int nqt = Nq >> 5;
    if ((int)blockIdx.x >= (nqt << ls)) return;
    const int qt = blockIdx.x >> ls;
    const int split = blockIdx.x & ((1 << ls) - 1);
    const int kchunk = Nk >> ls;       // multiple of 64
    const int h = threadIdx.x >> 6;
    const int lane = threadIdx.x & 63;
    const int cq = lane & 31;
    const int half = lane >> 5;
    const int h16 = h * 16;

    bf16x8 qb = *(const bf16x8*)(Q + ((size_t)(qt * 32 + cq) * D + h16 + half * 8));
    int drow = (cq < 16) ? (h16 + cq) : (cq == 16 ? 64 : h16 + 15);
    const unsigned short* vbase = Vt + (size_t)drow * Nk;

    f32x16 o, mC;
    #pragma unroll
    for (int i = 0; i < 16; ++i) { o[i] = 0.f; mC[i] = 0.f; }
    float m;

    const int kstart = split * kchunk;
    // ---- peeled first 64 keys: establish the (fixed) reference max ----
    {
        const int kb = kstart;
        bf16x8 ka0 = *(const bf16x8*)(K + ((size_t)(kb + cq) * D + h16 + half * 8));
        bf16x8 ka1 = *(const bf16x8*)(K + ((size_t)(kb + 32 + cq) * D + h16 + half * 8));
        f32x16 s0 = __builtin_amdgcn_mfma_f32_32x32x16_bf16(ka0, qb, mC, 0, 0, 0);
        f32x16 s1 = __builtin_amdgcn_mfma_f32_32x32x16_bf16(ka1, qb, mC, 0, 0, 0);
        float cm;
        MAXTREE(cm, s0, s1);
        #pragma unroll
        for (int off = 1; off < 64; off <<= 1) cm = fmaxf(cm, __shfl_xor(cm, off));
        m = cm;
        #pragma unroll
        for (int i = 0; i < 16; ++i) {
            s0[i] = fexp2(s0[i] - m);
            s1[i] = fexp2(s1[i] - m);
            mC[i] = -m;
        }
        PVPACK(s0, kb)
        PVPACK(s1, kb + 32)
    }
    // ---- branchless steady loop ----
    #pragma unroll 2
    for (int kb = kstart + 64; kb < kstart + kchunk; kb += 32) {
        bf16x8 ka = *(const bf16x8*)(K + ((size_t)(kb + cq) * D + h16 + half * 8));
        f32x16 s = __builtin_amdgcn_mfma_f32_32x32x16_bf16(ka, qb, mC, 0, 0, 0);
        #pragma unroll
        for (int i = 0; i < 16; ++i) s[i] = fexp2(s[i]);
        PVPACK(s, kb)
    }

    size_t pbase = (size_t)split * Nq + qt * 32;
    if (half == 0)
        pm[(pbase + cq) * 4 + h] = m;
    if (cq == 16) {
        #pragma unroll
        for (int r = 0; r < 16; ++r) {
            int qr = (r & 3) + 8 * (r >> 2) + 4 * half;
            pl[(pbase + qr) * 4 + h] = o[r];
        }
    }
    if (cq < 16) {
        #pragma unroll
        for (int r = 0; r < 16; ++r) {
            int qr = (r & 3) + 8 * (r >> 2) + 4 * half;
            po[(pbase + qr) * 64 + h16 + cq] = o[r];
        }
    }
}

// ---------------------------------------------------------------------------
// Combine split-K partials + residual -> dense h_c (plain float4 stores,
// NO atomics). Templated split count so the s-loop fully unrolls.
// ---------------------------------------------------------------------------
template<int NS>
__device__ __forceinline__ void comb_body(
        const float* __restrict__ po, const float* __restrict__ pm,
        const float* __restrict__ pl, int Nq,
        const float* __restrict__ resid, float* __restrict__ outc, int i) {
    int q = i >> 4;
    int part = i & 15;
    int d0 = part * 4;
    int h = part >> 2;
    float pmv[NS], plv[NS];
    #pragma unroll
    for (int s = 0; s < NS; ++s) pmv[s] = pm[((size_t)s * Nq + q) * 4 + h];
    #pragma unroll
    for (int s = 0; s < NS; ++s) plv[s] = pl[((size_t)s * Nq + q) * 4 + h];
    float M = pmv[0];
    #pragma unroll
    for (int s = 1; s < NS; ++s) M = fmaxf(M, pmv[s]);
    float4 O = {0.f, 0.f, 0.f, 0.f};
    float L = 0.f;
    #pragma unroll
    for (int s = 0; s < NS; ++s) {
        float wgt = fexp2(pmv[s] - M);
        float4 pv = *(const float4*)(po + ((size_t)s * Nq + q) * 64 + d0);
        O.x += pv.x * wgt; O.y += pv.y * wgt; O.z += pv.z * wgt; O.w += pv.w * wgt;
        L += plv[s] * wgt;
    }
    float invL = 1.0f / L;
    float4 rv = *(const float4*)(resid + (size_t)q * 64 + d0);
    float4 res;
    res.x = rv.x + O.x * invL;
    res.y = rv.y + O.y * invL;
    res.z = rv.z + O.z * invL;
    res.w = rv.w + O.w * invL;
    *(float4*)(outc + (size_t)q * 64 + d0) = res;
}

template<int NSM, int NSP>
__global__ void k_comb2t(
        const float* __restrict__ poM, const float* __restrict__ pmM, const float* __restrict__ plM,
        int Nm, const float* __restrict__ residM, float* __restrict__ outM,
        const float* __restrict__ poP, const float* __restrict__ pmP, const float* __restrict__ plP,
        int Np, const float* __restrict__ residP, float* __restrict__ outP) {
    int idx = blockIdx.x * blockDim.x + threadIdx.x;
    int mtot = Nm * 16;
    if (idx < mtot)
        comb_body<NSM>(poM, pmM, plM, Nm, residM, outM, idx);
    else if (idx - mtot < Np * 16)
        comb_body<NSP>(poP, pmP, plP, Np, residP, outP, idx - mtot);
}

// Generic fallback (runtime ns, scalar path)
__global__ void k_comb2(
        const float* __restrict__ poM, const float* __restrict__ pmM, const float* __restrict__ plM,
        int nsM, int Nm, const float* __restrict__ residM, float* __restrict__ outM,
        const float* __restrict__ poP, const float* __restrict__ pmP, const float* __restrict__ plP,
        int nsP, int Np, const float* __restrict__ residP, float* __restrict__ outP) {
    int idx = blockIdx.x * blockDim.x + threadIdx.x;
    const float *po, *pm, *pl, *resid;
    float* outc;
    int ns, Nq, i;
    int mtot = Nm * 64;
    if (idx < mtot) {
        po = poM; pm = pmM; pl = plM; ns = nsM; Nq = Nm; resid = residM; outc = outM; i = idx;
    } else {
        i = idx - mtot;
        if (i >= Np * 64) return;
        po = poP; pm = pmP; pl = plP; ns = nsP; Nq = Np; resid = residP; outc = outP;
    }
    int q = i >> 6, d = i & 63, h = d >> 4;
    float M = -1e30f;
    for (int s = 0; s < ns; ++s)
        M = fmaxf(M, pm[((size_t)s * Nq + q) * 4 + h]);
    float O = 0.f, L = 0.f;
    for (int s = 0; s < ns; ++s) {
        float wgt = fexp2(pm[((size_t)s * Nq + q) * 4 + h] - M);
        O += po[((size_t)s * Nq + q) * 64 + d] * wgt;
        L += pl[((size_t)s * Nq + q) * 4 + h] * wgt;
    }
    outc[i] = resid[i] + O / L;
}

// ---------------------------------------------------------------------------
// Per-batch pooling over sorted batch ranges: one block per (batch, graph).
// Direct stores, zero atomics.
// ---------------------------------------------------------------------------
__global__ __launch_bounds__(256) void k_pool2(
        const float* __restrict__ hM, const int* __restrict__ bsM,
        const float* __restrict__ hP, const int* __restrict__ bsP,
        float* __restrict__ zsum, float* __restrict__ zcnt) {
    __shared__ float red[4][64];
    int b = blockIdx.x & 63;
    int isP = blockIdx.x >> 6;
    const float* h = isP ? hP : hM;
    const int* bs = isP ? bsP : bsM;
    int colOff = isP ? 64 : 0;
    int n0 = bs[b], n1 = bs[b + 1];
    int w = threadIdx.x >> 6, c = threadIdx.x & 63;
    float acc = 0.f;
    for (int n = n0 + w; n < n1; n += 4)
        acc += h[(size_t)n * 64 + c];
    red[w][c] = acc;
    __syncthreads();
    if (w == 0) {
        float s = (red[0][c] + red[1][c]) + (red[2][c] + red[3][c]);
        zsum[b * 128 + colOff + c] = s;
        if (c == 0) zcnt[b * 2 + isP] = (float)(n1 - n0);
    }
}

// ---------------------------------------------------------------------------
// Head MLP: one wave per batch element
// ---------------------------------------------------------------------------
__global__ __launch_bounds__(256) void k_head2(
        const float* __restrict__ zsum, const float* __restrict__ zcnt,
        const float* __restrict__ fc1w, const float* __restrict__ fc1b,
        const float* __restrict__ fc2w, const float* __restrict__ fc2b,
        float* __restrict__ out) {
    int b = blockIdx.x * 4 + (threadIdx.x >> 6);
    int c = threadIdx.x & 63;
    float inv0 = 1.0f / fmaxf(zcnt[b * 2 + 0], 1.0f);
    float inv1 = 1.0f / fmaxf(zcnt[b * 2 + 1], 1.0f);
    float acc = fc1b[c];
    #pragma unroll 8
    for (int k = 0; k < 128; ++k) {
        float zv = zsum[b * 128 + k] * (k < 64 ? inv0 : inv1);
        acc += zv * fc1w[k * 64 + c];
    }
    float v = fmaxf(acc, 0.0f) * fc2w[c];
    #pragma unroll
    for (int off = 32; off > 0; off >>= 1) v += __shfl_xor(v, off);
    if (c == 0) out[b] = 1.0f / (1.0f + __expf(-(v + fc2b[0])));
}

// ---------------------------------------------------------------------------
extern "C" void kernel_launch(void* const* d_in, const int* in_sizes, int n_in,
                              void* d_out, int out_size, void* d_ws, size_t ws_size,
                              hipStream_t stream) {
    const float* x_mol  = (const float*)d_in[0];
    const float* x_prot = (const float*)d_in[1];
    const float* m1_wl = (const float*)d_in[2];
    const float* m1_bl = (const float*)d_in[3];
    const float* m1_wr = (const float*)d_in[4];
    const float* m2_wl = (const float*)d_in[5];
    const float* m2_bl = (const float*)d_in[6];
    const float* m2_wr = (const float*)d_in[7];
    const float* p1_wl = (const float*)d_in[8];
    const float* p1_bl = (const float*)d_in[9];
    const float* p1_wr = (const float*)d_in[10];
    const float* p2_wl = (const float*)d_in[11];
    const float* p2_bl = (const float*)d_in[12];
    const float* p2_wr = (const float*)d_in[13];
    const float* amp_w = (const float*)d_in[14];
    const float* amp_b = (const float*)d_in[15];
    const float* apm_w = (const float*)d_in[16];
    const float* apm_b = (const float*)d_in[17];
    const float* fc1_w = (const float*)d_in[18];
    const float* fc1_b = (const float*)d_in[19];
    const float* fc2_w = (const float*)d_in[20];
    const float* fc2_b = (const float*)d_in[21];
    const int* edge_mol  = (const int*)d_in[22];
    const int* edge_prot = (const int*)d_in[23];
    const int* batch_mol  = (const int*)d_in[24];
    const int* batch_prot = (const int*)d_in[25];
    float* out = (float*)d_out;

    const int N_MOL  = in_sizes[0] / 32;
    const int N_PROT = in_sizes[1] / 64;
    const int E_MOL  = in_sizes[22] / 2;
    const int E_PROT = in_sizes[23] / 2;

    // ---- workspace bump allocator ----
    char* base = (char*)d_ws;
    size_t off = 0;
    auto alloc = [&](size_t bytes) -> void* {
        void* p = base + off;
        off = (off + bytes + 255) & ~(size_t)255;
        return p;
    };
    float* h_mol1   = (float*)alloc((size_t)N_MOL * D * sizeof(float));
    float* h_mol2   = (float*)alloc((size_t)N_MOL * D * sizeof(float));
    float* h_prot1  = (float*)alloc((size_t)N_PROT * D * sizeof(float));
    float* h_prot2  = (float*)alloc((size_t)N_PROT * D * sizeof(float));
    float* h_mol_c  = (float*)alloc((size_t)N_MOL * D * sizeof(float));
    float* h_prot_c = (float*)alloc((size_t)N_PROT * D * sizeof(float));
    float* zsum     = (float*)alloc((NB * 128 + NB * 2) * sizeof(float));
    float* zcnt     = zsum + NB * 128;
    unsigned short* Qm_b = (unsigned short*)alloc((size_t)N_MOL * D * 2);
    unsigned short* Km_b = (unsigned short*)alloc((size_t)N_MOL * D * 2);
    unsigned short* Vm_b = (unsigned short*)alloc((size_t)N_MOL * D * 2);
    unsigned short* Vm_t = (unsigned short*)alloc((size_t)N_MOL * (D + 1) * 2);
    unsigned short* Qp_b = (unsigned short*)alloc((size_t)N_PROT * D * 2);
    unsigned short* Kp_b = (unsigned short*)alloc((size_t)N_PROT * D * 2);
    unsigned short* Vp_b = (unsigned short*)alloc((size_t)N_PROT * D * 2);
    unsigned short* Vp_t = (unsigned short*)alloc((size_t)N_PROT * (D + 1) * 2);
    // CSR
    int* deg      = (int*)alloc(((size_t)N_MOL + N_PROT) * sizeof(int));
    int* deg_m    = deg;
    int* deg_p    = deg + N_MOL;
    int* rp_m     = (int*)alloc(((size_t)N_MOL + 1) * sizeof(int));
    int* cur_m    = (int*)alloc((size_t)N_MOL * sizeof(int));
    int* csr_m    = (int*)alloc((size_t)E_MOL * sizeof(int));
    int* rp_p     = (int*)alloc(((size_t)N_PROT + 1) * sizeof(int));
    int* cur_p    = (int*)alloc((size_t)N_PROT * sizeof(int));
    int* csr_p    = (int*)alloc((size_t)E_PROT * sizeof(int));
    int* bsM      = (int*)alloc((NB + 1) * sizeof(int));
    int* bsP      = (int*)alloc((NB + 1) * sizeof(int));

    // split-K factors (keys per split must be a multiple of 64)
    int nsm = 16; while (nsm > 1 && (N_PROT % (64 * nsm))) nsm >>= 1;  // mol queries prot keys
    int nsp = 4;  while (nsp > 1 && (N_MOL % (64 * nsp)))  nsp >>= 1;  // prot queries mol keys
    int lsm = 31 - __builtin_clz(nsm);
    int lsp = 31 - __builtin_clz(nsp);
    float* poM = (float*)alloc((size_t)nsm * N_MOL * 64 * sizeof(float));
    float* pmM = (float*)alloc((size_t)nsm * N_MOL * 4 * sizeof(float));
    float* plM = (float*)alloc((size_t)nsm * N_MOL * 4 * sizeof(float));
    float* poP = (float*)alloc((size_t)nsp * N_PROT * 64 * sizeof(float));
    float* pmP = (float*)alloc((size_t)nsp * N_PROT * 4 * sizeof(float));
    float* plP = (float*)alloc((size_t)nsp * N_PROT * 4 * sizeof(float));

    const int BLK = 256;
    dim3 blk(BLK);
    const float QS = 0.25f * 1.4426950408889634f;  // 1/sqrt(DH) * log2(e)

    // ---- CSR build + batch starts ----
    hipMemsetAsync(deg, 0, ((size_t)N_MOL + N_PROT) * sizeof(int), stream);
    int Etot = E_MOL + E_PROT;
    k_prep2<<<(Etot + BLK - 1) / BLK, blk, 0, stream>>>(
        edge_mol, E_MOL, edge_prot, E_PROT, deg_m, deg_p,
        batch_mol, N_MOL, bsM, batch_prot, N_PROT, bsP);
    k_scan2<<<2, blk, 0, stream>>>(deg_m, N_MOL, rp_m, cur_m, deg_p, N_PROT, rp_p, cur_p);
    k_scatter2<<<(Etot + BLK - 1) / BLK, blk, 0, stream>>>(edge_mol, E_MOL, cur_m, csr_m,
                                                           edge_prot, E_PROT, cur_p, csr_p);

    // ---- SAGE layers (mol + prot merged per layer) ----
    k_gsage2<32, 64><<<N_MOL / 4 + N_PROT / 4, blk, 0, stream>>>(
        x_mol,  rp_m, csr_m, N_MOL,  m1_wl, m1_bl, m1_wr, h_mol1,
        x_prot, rp_p, csr_p, N_PROT, p1_wl, p1_bl, p1_wr, h_prot1);
    k_gsage2<64, 64><<<N_MOL / 4 + N_PROT / 4, blk, 0, stream>>>(
        h_mol1,  rp_m, csr_m, N_MOL,  m2_wl, m2_bl, m2_wr, h_mol2,
        h_prot1, rp_p, csr_p, N_PROT, p2_wl, p2_bl, p2_wr, h_prot2);

    // ---- QKV projections (merged) ----
    k_qkv2<<<N_MOL / 16 + N_PROT / 16, blk, 0, stream>>>(
        h_mol2, N_MOL, h_prot2, N_PROT, amp_w, amp_b, apm_w, apm_b, QS,
        Qm_b, Km_b, Vm_b, Qp_b, Kp_b, Vp_b);

    // ---- V transposes (merged, permuted, + ones row) ----
    k_transp2<<<N_MOL / 64 + N_PROT / 64, blk, 0, stream>>>(Vm_b, Vm_t, N_MOL, Vp_b, Vp_t, N_PROT);

    // ---- split-K flash attention (both directions, one launch) ----
    int gxm = (N_MOL / 32) * nsm;
    int gxp = (N_PROT / 32) * nsp;
    int gx = gxm > gxp ? gxm : gxp;
    k_attn5<<<dim3(gx, 2), blk, 0, stream>>>(
        Qm_b, Kp_b, Vp_t, N_MOL, N_PROT, lsm, poM, pmM, plM,
        Qp_b, Km_b, Vm_t, lsp, poP, pmP, plP);

    // ---- combine + residual -> h_c (no atomics) ----
    if (nsm == 16 && nsp == 4) {
        int tot = (N_MOL + N_PROT) * 16;
        k_comb2t<16, 4><<<(tot + BLK - 1) / BLK, blk, 0, stream>>>(
            poM, pmM, plM, N_MOL, h_mol2, h_mol_c,
            poP, pmP, plP, N_PROT, h_prot2, h_prot_c);
    } else {
        k_comb2<<<((N_MOL + N_PROT) * 64 + BLK - 1) / BLK, blk, 0, stream>>>(
            poM, pmM, plM, nsm, N_MOL, h_mol2, h_mol_c,
            poP, pmP, plP, nsp, N_PROT, h_prot2, h_prot_c);
    }

    // ---- per-batch pooling (no atomics) ----
    k_pool2<<<128, blk, 0, stream>>>(h_mol_c, bsM, h_prot_c, bsP, zsum, zcnt);

    // ---- head ----
    k_head2<<<16, blk, 0, stream>>>(zsum, zcnt, fc1_w, fc1_b, fc2_w, fc2_b, out);
}

// Round 15
// 171.859 us; speedup vs baseline: 1.0322x; 1.0140x over previous
//
#include <hip/hip_runtime.h>
#include <math.h>

#define D 64
#define NB 64

typedef __attribute__((ext_vector_type(8))) short bf16x8;
typedef __attribute__((ext_vector_type(4))) float f32x4;
typedef __attribute__((ext_vector_type(16))) float f32x16;

#define M3(a, b, c) fmaxf(fmaxf((a), (b)), (c))

__device__ __forceinline__ unsigned short f2bf(float f) {
    unsigned u = __float_as_uint(f);
    u += 0x7FFF + ((u >> 16) & 1);
    return (unsigned short)(u >> 16);
}
__device__ __forceinline__ unsigned pk_bf16(float lo, float hi) {
    unsigned r;
    asm("v_cvt_pk_bf16_f32 %0, %1, %2" : "=v"(r) : "v"(lo), "v"(hi));
    return r;
}
__device__ __forceinline__ float fexp2(float x) {
    float r;
    asm("v_exp_f32 %0, %1" : "=v"(r) : "v"(x));
    return r;
}

// ---------------------------------------------------------------------------
// Prep: dst-degree histogram (both graphs) + batch start offsets (sorted ids)
// ---------------------------------------------------------------------------
__global__ void k_prep2(const int* __restrict__ em, int Em,
                        const int* __restrict__ ep, int Ep,
                        int* __restrict__ degm, int* __restrict__ degp,
                        const int* __restrict__ bm, int Nm, int* __restrict__ bsM,
                        const int* __restrict__ bp, int Np, int* __restrict__ bsP) {
    int i = blockIdx.x * blockDim.x + threadIdx.x;
    if (i < Em) atomicAdd(&degm[em[Em + i]], 1);
    int j = i - Em;
    if (j >= 0 && j < Ep) atomicAdd(&degp[ep[Ep + j]], 1);
    if (i < Nm) {
        int cur = bm[i];
        int prev = (i == 0) ? -1 : bm[i - 1];
        for (int b = prev + 1; b <= cur; ++b) bsM[b] = i;
        if (i == Nm - 1)
            for (int b = cur + 1; b <= NB; ++b) bsM[b] = Nm;
    }
    int j2 = i - Nm;
    if (j2 >= 0 && j2 < Np) {
        int cur = bp[j2];
        int prev = (j2 == 0) ? -1 : bp[j2 - 1];
        for (int b = prev + 1; b <= cur; ++b) bsP[b] = j2;
        if (j2 == Np - 1)
            for (int b = cur + 1; b <= NB; ++b) bsP[b] = Np;
    }
}

// ---------------------------------------------------------------------------
// CSR build: exclusive prefix sum (block 0 = mol, block 1 = prot)
// ---------------------------------------------------------------------------
__global__ __launch_bounds__(256) void k_scan2(
        const int* __restrict__ degm, int Nm, int* __restrict__ rpm, int* __restrict__ curm,
        const int* __restrict__ degp, int Np, int* __restrict__ rpp, int* __restrict__ curp) {
    __shared__ int sdeg[8192];
    __shared__ int chunk[256];
    const int* deg = blockIdx.x ? degp : degm;
    int N = blockIdx.x ? Np : Nm;
    int* rowptr = blockIdx.x ? rpp : rpm;
    int* cursor = blockIdx.x ? curp : curm;
    int t = threadIdx.x;
    for (int i = t; i < N; i += 256) sdeg[i] = deg[i];
    __syncthreads();
    int C = (N + 255) / 256;
    int start = t * C;
    int sum = 0;
    for (int i = 0; i < C; ++i)
        if (start + i < N) sum += sdeg[start + i];
    chunk[t] = sum;
    __syncthreads();
    for (int ofs = 1; ofs < 256; ofs <<= 1) {
        int v = (t >= ofs) ? chunk[t - ofs] : 0;
        __syncthreads();
        chunk[t] += v;
        __syncthreads();
    }
    int base = (t == 0) ? 0 : chunk[t - 1];
    for (int i = 0; i < C && start + i < N; ++i) {
        rowptr[start + i] = base;
        cursor[start + i] = base;
        base += sdeg[start + i];
    }
    if (t == 255) rowptr[N] = base;
}

// ---------------------------------------------------------------------------
// CSR build: scatter src indices (both graphs, one launch)
// ---------------------------------------------------------------------------
__global__ void k_scatter2(const int* __restrict__ em, int Em, int* __restrict__ curm,
                           int* __restrict__ csrm,
                           const int* __restrict__ ep, int Ep, int* __restrict__ curp,
                           int* __restrict__ csrp) {
    int i = blockIdx.x * blockDim.x + threadIdx.x;
    if (i < Em) {
        int s = em[i], d = em[Em + i];
        csrm[atomicAdd(&curm[d], 1)] = s;
    }
    int j = i - Em;
    if (j >= 0 && j < Ep) {
        int s = ep[j], d = ep[Ep + j];
        csrp[atomicAdd(&curp[d], 1)] = s;
    }
}

// ---------------------------------------------------------------------------
// Fused gather + SAGE linear body (one wave per row)
// ---------------------------------------------------------------------------
template<int FIN>
__device__ __forceinline__ void gsage_body(
        const float* __restrict__ x, const int* __restrict__ rowptr,
        const int* __restrict__ csr, int N,
        const float* __restrict__ wl, const float* __restrict__ bl,
        const float* __restrict__ wr, float* __restrict__ out,
        int blk, float* __restrict__ swl, float* __restrict__ swr,
        float* __restrict__ sagg, float* __restrict__ sx) {
    for (int i = threadIdx.x; i < FIN * D; i += 256) { swl[i] = wl[i]; swr[i] = wr[i]; }
    int w = threadIdx.x >> 6;
    int lane = threadIdx.x & 63;
    int r = blk * 4 + w;
    if (r < N) {
        int e0 = rowptr[r], e1 = rowptr[r + 1];
        float inv = 1.0f / fmaxf((float)(e1 - e0), 1.0f);
        if (FIN == 64) {
            float a0 = 0.f, a1 = 0.f, a2 = 0.f, a3 = 0.f;
            int e = e0;
            for (; e + 3 < e1; e += 4) {
                a0 += x[(size_t)csr[e] * FIN + lane];
                a1 += x[(size_t)csr[e + 1] * FIN + lane];
                a2 += x[(size_t)csr[e + 2] * FIN + lane];
                a3 += x[(size_t)csr[e + 3] * FIN + lane];
            }
            for (; e < e1; ++e) a0 += x[(size_t)csr[e] * FIN + lane];
            sagg[w * 64 + lane] = ((a0 + a1) + (a2 + a3)) * inv;
            sx[w * 64 + lane] = x[(size_t)r * FIN + lane];
        } else {
            int f = lane & 31, half = lane >> 5;
            float a = 0.f;
            for (int e = e0 + half; e < e1; e += 2)
                a += x[(size_t)csr[e] * FIN + f];
            a += __shfl_xor(a, 32);
            if (half == 0) {
                sagg[w * 64 + f] = a * inv;
                sx[w * 64 + f] = x[(size_t)r * FIN + f];
            }
        }
    }
    __syncthreads();
    if (r >= N) return;
    int c = lane;
    float acc = bl[c];
    #pragma unroll 8
    for (int k = 0; k < FIN; ++k) {
        acc += sagg[w * 64 + k] * swl[k * D + c];
        acc += sx[w * 64 + k] * swr[k * D + c];
    }
    out[(size_t)r * D + c] = fmaxf(acc, 0.0f);
}

template<int FA, int FB>
__global__ __launch_bounds__(256) void k_gsage2(
        const float* __restrict__ xA, const int* __restrict__ rpA,
        const int* __restrict__ csrA, int NA,
        const float* __restrict__ wlA, const float* __restrict__ blA,
        const float* __restrict__ wrA, float* __restrict__ outA,
        const float* __restrict__ xB, const int* __restrict__ rpB,
        const int* __restrict__ csrB, int NB_,
        const float* __restrict__ wlB, const float* __restrict__ blB,
        const float* __restrict__ wrB, float* __restrict__ outB) {
    __shared__ float swl[64 * 64];
    __shared__ float swr[64 * 64];
    __shared__ float sagg[4 * 64];
    __shared__ float sx[4 * 64];
    int bA = NA / 4;
    if ((int)blockIdx.x < bA)
        gsage_body<FA>(xA, rpA, csrA, NA, wlA, blA, wrA, outA, blockIdx.x, swl, swr, sagg, sx);
    else
        gsage_body<FB>(xB, rpB, csrB, NB_, wlB, blB, wrB, outB, blockIdx.x - bA, swl, swr, sagg, sx);
}

// ---------------------------------------------------------------------------
// Fused QKV projection -> bf16 (Q pre-scaled), both graphs in one launch.
// ---------------------------------------------------------------------------
__global__ __launch_bounds__(256) void k_qkv2(
        const float* __restrict__ xA, int NA, const float* __restrict__ xB, int NB_,
        const float* __restrict__ amp_w, const float* __restrict__ amp_b,
        const float* __restrict__ apm_w, const float* __restrict__ apm_b, float qs,
        unsigned short* __restrict__ QA, unsigned short* __restrict__ KA, unsigned short* __restrict__ VA,
        unsigned short* __restrict__ QB, unsigned short* __restrict__ KB, unsigned short* __restrict__ VB) {
    __shared__ float sq[D * D], sk[D * D], sv[D * D], sx[16 * D];
    int bA = NA / 16;
    const float *x, *wq, *bq, *wk, *bk, *wv, *bv;
    unsigned short *oq, *ok, *ov;
    int blk;
    if ((int)blockIdx.x < bA) {
        x = xA; blk = blockIdx.x;
        wq = amp_w;        bq = amp_b;
        wk = apm_w + 4096; bk = apm_b + 64;
        wv = apm_w + 8192; bv = apm_b + 128;
        oq = QA; ok = KA; ov = VA;
    } else {
        x = xB; blk = blockIdx.x - bA;
        wq = apm_w;        bq = apm_b;
        wk = amp_w + 4096; bk = amp_b + 64;
        wv = amp_w + 8192; bv = amp_b + 128;
        oq = QB; ok = KB; ov = VB;
    }
    for (int i = threadIdx.x; i < D * D; i += 256) { sq[i] = wq[i]; sk[i] = wk[i]; sv[i] = wv[i]; }
    int rbase = blk * 16;
    for (int i = threadIdx.x; i < 16 * D; i += 256) sx[i] = x[(size_t)rbase * D + i];
    __syncthreads();
    int c = threadIdx.x & 63;
    int r0 = (threadIdx.x >> 6) * 4;
    for (int rr = 0; rr < 4; ++rr) {
        int r = r0 + rr;
        float aq = bq[c], ak = bk[c], av = bv[c];
        #pragma unroll 8
        for (int k = 0; k < D; ++k) {
            float xv = sx[r * D + k];
            aq += xv * sq[k * D + c];
            ak += xv * sk[k * D + c];
            av += xv * sv[k * D + c];
        }
        size_t o = (size_t)(rbase + r) * D + c;
        oq[o] = f2bf(aq * qs);
        ok[o] = f2bf(ak);
        ov[o] = f2bf(av);
    }
}

// ---------------------------------------------------------------------------
// V transpose [N,64] -> [65,N] bf16 (row 64 = ones for the l-column trick),
// with within-32-chunk key permutation (swap bit2<->bit3) so the attn
// kernel's natural cvt_pk packing of scores IS the PV A-fragment.
// ---------------------------------------------------------------------------
__global__ void k_transp2(const unsigned short* __restrict__ inM, unsigned short* __restrict__ outM, int Nm,
                          const unsigned short* __restrict__ inP, unsigned short* __restrict__ outP, int Np) {
    __shared__ unsigned short tile[64][72];
    int bm = Nm >> 6;
    const unsigned short* in; unsigned short* out; int N;
    int blk = blockIdx.x;
    if (blk < bm) { in = inM; out = outM; N = Nm; }
    else { blk -= bm; in = inP; out = outP; N = Np; }
    int t = threadIdx.x;
    int rbase = blk * 64;
    {
        int r = t >> 2, c0 = (t & 3) * 16;
        const uint4* src = (const uint4*)(in + (size_t)(rbase + r) * 64 + c0);
        uint4 a = src[0], b = src[1];
        *(uint4*)(&tile[r][c0]) = a;
        *(uint4*)(&tile[r][c0 + 8]) = b;
    }
    __syncthreads();
    {
        int c = t >> 2, r0 = (t & 3) * 16;
        union { uint2 v2[4]; unsigned short s[16]; } u;
        #pragma unroll
        for (int i = 0; i < 16; ++i) u.s[i] = tile[r0 + i][c];
        int key0 = rbase + r0;
        int kc = key0 & ~31;
        int b16 = key0 & 16;
        unsigned short* op = out + (size_t)c * N;
        const int gmap[4] = {0, 8, 4, 12};
        #pragma unroll
        for (int b = 0; b < 4; ++b)
            *(uint2*)(op + kc + b16 + gmap[b]) = u.v2[b];
    }
    if (t < 8) {
        uint4 ones;
        ones.x = ones.y = ones.z = ones.w = 0x3F803F80u;  // bf16 1.0 pairs
        *(uint4*)(out + (size_t)64 * N + rbase + t * 8) = ones;
    }
}

// ---------------------------------------------------------------------------
// Split-K flash attention, 32x32x16 MFMA. 512-thread blocks: 8 waves =
// 2 query-tiles x 4 heads (tests block-residency occupancy cap; grids for
// both directions become exactly 512 blocks - no dead blocks).
// Body = measured-best config: 64-key iters, bias via MFMA C operand,
// deferred-max (T13), single accumulator, setprio around PV.
// ---------------------------------------------------------------------------
#define MAXTREE(cm, s0, s1)                                                   \
    {                                                                         \
        float c0 = M3(s0[0], s0[1], s0[2]);                                   \
        float c1 = M3(s0[3], s0[4], s0[5]);                                   \
        float c2 = M3(s0[6], s0[7], s0[8]);                                   \
        float c3 = M3(s0[9], s0[10], s0[11]);                                 \
        float c4 = M3(s0[12], s0[13], s0[14]);                                \
        float c5 = M3(s0[15], s1[0], s1[1]);                                  \
        float c6 = M3(s1[2], s1[3], s1[4]);                                   \
        float c7 = M3(s1[5], s1[6], s1[7]);                                   \
        float c8 = M3(s1[8], s1[9], s1[10]);                                  \
        float c9 = M3(s1[11], s1[12], s1[13]);                                \
        float ca = fmaxf(s1[14], s1[15]);                                     \
        float d0 = M3(c0, c1, c2);                                            \
        float d1 = M3(c3, c4, c5);                                            \
        float d2 = M3(c6, c7, c8);                                            \
        float d3 = M3(c9, ca, d0);                                            \
        cm = M3(d1, d2, d3);                                                  \
    }

#define PVPACK(S, KB)                                                         \
    {                                                                         \
        union { unsigned u[4]; bf16x8 v; } f1, f2;                            \
        f1.u[0] = pk_bf16((S)[0], (S)[1]);   f1.u[1] = pk_bf16((S)[2], (S)[3]);  \
        f1.u[2] = pk_bf16((S)[4], (S)[5]);   f1.u[3] = pk_bf16((S)[6], (S)[7]);  \
        f2.u[0] = pk_bf16((S)[8], (S)[9]);   f2.u[1] = pk_bf16((S)[10], (S)[11]);\
        f2.u[2] = pk_bf16((S)[12], (S)[13]); f2.u[3] = pk_bf16((S)[14], (S)[15]);\
        bf16x8 vb0 = *(const bf16x8*)(vbase + (KB) + half * 8);               \
        bf16x8 vb1 = *(const bf16x8*)(vbase + (KB) + 16 + half * 8);          \
        __builtin_amdgcn_s_setprio(1);                                        \
        o = __builtin_amdgcn_mfma_f32_32x32x16_bf16(f1.v, vb0, o, 0, 0, 0);   \
        o = __builtin_amdgcn_mfma_f32_32x32x16_bf16(f2.v, vb1, o, 0, 0, 0);   \
        __builtin_amdgcn_s_setprio(0);                                        \
    }

__global__ __launch_bounds__(512) void k_attn6(
        const unsigned short* __restrict__ QmB, const unsigned short* __restrict__ KpB,
        const unsigned short* __restrict__ VpT, int Nm, int Np, int lsm,
        float* __restrict__ poM, float* __restrict__ pmM, float* __restrict__ plM,
        const unsigned short* __restrict__ QpB, const unsigned short* __restrict__ KmB,
        const unsigned short* __restrict__ VmT, int lsp,
        float* __restrict__ poP, float* __restrict__ pmP, float* __restrict__ plP) {
    const unsigned short *Q, *K, *Vt;
    int Nq, Nk, ls;
    float *po, *pm, *pl;
    if (blockIdx.y == 0) { Q = QmB; K = KpB; Vt = VpT; Nq = Nm; Nk = Np; ls = lsm; po = poM; pm = pmM; pl = plM; }
    else                 { Q = QpB; K = KmB; Vt = VmT; Nq = Np; Nk = Nm; ls = lsp; po = poP; pm = pmP; pl = plP; }
    int npair = Nq >> 6;   // query-tile pairs
    if ((int)blockIdx.x >= (npair << ls)) return;
    const int qpair = blockIdx.x >> ls;
    const int split = blockIdx.x & ((1 << ls) - 1);
    const int kchunk = Nk >> ls;       // multiple of 64
    const int w = threadIdx.x >> 6;    // 0..7
    const int h = w & 3;
    const int qt = qpair * 2 + (w >> 2);
    const int lane = threadIdx.x & 63;
    const int cq = lane & 31;
    const int half = lane >> 5;
    const int h16 = h * 16;

    bf16x8 qb = *(const bf16x8*)(Q + ((size_t)(qt * 32 + cq) * D + h16 + half * 8));
    int drow = (cq < 16) ? (h16 + cq) : (cq == 16 ? 64 : h16 + 15);
    const unsigned short* vbase = Vt + (size_t)drow * Nk;

    f32x16 o, mC;
    #pragma unroll
    for (int i = 0; i < 16; ++i) { o[i] = 0.f; mC[i] = 0.f; }
    float m;

    const int kstart = split * kchunk;
    // ---- peeled first 64 keys ----
    {
        const int kb = kstart;
        bf16x8 ka0 = *(const bf16x8*)(K + ((size_t)(kb + cq) * D + h16 + half * 8));
        bf16x8 ka1 = *(const bf16x8*)(K + ((size_t)(kb + 32 + cq) * D + h16 + half * 8));
        f32x16 s0 = __builtin_amdgcn_mfma_f32_32x32x16_bf16(ka0, qb, mC, 0, 0, 0);
        f32x16 s1 = __builtin_amdgcn_mfma_f32_32x32x16_bf16(ka1, qb, mC, 0, 0, 0);
        float cm;
        MAXTREE(cm, s0, s1);
        #pragma unroll
        for (int off = 1; off < 64; off <<= 1) cm = fmaxf(cm, __shfl_xor(cm, off));
        m = cm;
        #pragma unroll
        for (int i = 0; i < 16; ++i) {
            s0[i] = fexp2(s0[i] - m);
            s1[i] = fexp2(s1[i] - m);
            mC[i] = -m;
        }
        PVPACK(s0, kb)
        PVPACK(s1, kb + 32)
    }
    for (int kb = kstart + 64; kb < kstart + kchunk; kb += 64) {
        bf16x8 ka0 = *(const bf16x8*)(K + ((size_t)(kb + cq) * D + h16 + half * 8));
        bf16x8 ka1 = *(const bf16x8*)(K + ((size_t)(kb + 32 + cq) * D + h16 + half * 8));
        f32x16 s0 = __builtin_amdgcn_mfma_f32_32x32x16_bf16(ka0, qb, mC, 0, 0, 0);
        f32x16 s1 = __builtin_amdgcn_mfma_f32_32x32x16_bf16(ka1, qb, mC, 0, 0, 0);
        float cm;
        MAXTREE(cm, s0, s1);
        if (__any(cm > 8.f)) {            // deferred-max rescale (T13)
            float cw = cm;
            #pragma unroll
            for (int off = 1; off < 64; off <<= 1) cw = fmaxf(cw, __shfl_xor(cw, off));
            float nm = fmaxf(m + cw, m);
            float sc = fexp2(m - nm);
            #pragma unroll
            for (int i = 0; i < 16; ++i) o[i] *= sc;
            float dl = nm - m;
            #pragma unroll
            for (int i = 0; i < 16; ++i) { s0[i] -= dl; s1[i] -= dl; mC[i] = -nm; }
            m = nm;
        }
        #pragma unroll
        for (int i = 0; i < 16; ++i) { s0[i] = fexp2(s0[i]); s1[i] = fexp2(s1[i]); }
        PVPACK(s0, kb)
        PVPACK(s1, kb + 32)
    }

    size_t pbase = (size_t)split * Nq + qt * 32;
    if (half == 0)
        pm[(pbase + cq) * 4 + h] = m;
    if (cq == 16) {
        #pragma unroll
        for (int r = 0; r < 16; ++r) {
            int qr = (r & 3) + 8 * (r >> 2) + 4 * half;
            pl[(pbase + qr) * 4 + h] = o[r];
        }
    }
    if (cq < 16) {
        #pragma unroll
        for (int r = 0; r < 16; ++r) {
            int qr = (r & 3) + 8 * (r >> 2) + 4 * half;
            po[(pbase + qr) * 64 + h16 + cq] = o[r];
        }
    }
}

// ---------------------------------------------------------------------------
// Combine split-K partials + residual -> dense h_c (plain float4 stores,
// NO atomics). Templated split count so the s-loop fully unrolls.
// ---------------------------------------------------------------------------
template<int NS>
__device__ __forceinline__ void comb_body(
        const float* __restrict__ po, const float* __restrict__ pm,
        const float* __restrict__ pl, int Nq,
        const float* __restrict__ resid, float* __restrict__ outc, int i) {
    int q = i >> 4;
    int part = i & 15;
    int d0 = part * 4;
    int h = part >> 2;
    float pmv[NS], plv[NS];
    #pragma unroll
    for (int s = 0; s < NS; ++s) pmv[s] = pm[((size_t)s * Nq + q) * 4 + h];
    #pragma unroll
    for (int s = 0; s < NS; ++s) plv[s] = pl[((size_t)s * Nq + q) * 4 + h];
    float M = pmv[0];
    #pragma unroll
    for (int s = 1; s < NS; ++s) M = fmaxf(M, pmv[s]);
    float4 O = {0.f, 0.f, 0.f, 0.f};
    float L = 0.f;
    #pragma unroll
    for (int s = 0; s < NS; ++s) {
        float wgt = fexp2(pmv[s] - M);
        float4 pv = *(const float4*)(po + ((size_t)s * Nq + q) * 64 + d0);
        O.x += pv.x * wgt; O.y += pv.y * wgt; O.z += pv.z * wgt; O.w += pv.w * wgt;
        L += plv[s] * wgt;
    }
    float invL = 1.0f / L;
    float4 rv = *(const float4*)(resid + (size_t)q * 64 + d0);
    float4 res;
    res.x = rv.x + O.x * invL;
    res.y = rv.y + O.y * invL;
    res.z = rv.z + O.z * invL;
    res.w = rv.w + O.w * invL;
    *(float4*)(outc + (size_t)q * 64 + d0) = res;
}

template<int NSM, int NSP>
__global__ void k_comb2t(
        const float* __restrict__ poM, const float* __restrict__ pmM, const float* __restrict__ plM,
        int Nm, const float* __restrict__ residM, float* __restrict__ outM,
        const float* __restrict__ poP, const float* __restrict__ pmP, const float* __restrict__ plP,
        int Np, const float* __restrict__ residP, float* __restrict__ outP) {
    int idx = blockIdx.x * blockDim.x + threadIdx.x;
    int mtot = Nm * 16;
    if (idx < mtot)
        comb_body<NSM>(poM, pmM, plM, Nm, residM, outM, idx);
    else if (idx - mtot < Np * 16)
        comb_body<NSP>(poP, pmP, plP, Np, residP, outP, idx - mtot);
}

// Generic fallback (runtime ns, scalar path)
__global__ void k_comb2(
        const float* __restrict__ poM, const float* __restrict__ pmM, const float* __restrict__ plM,
        int nsM, int Nm, const float* __restrict__ residM, float* __restrict__ outM,
        const float* __restrict__ poP, const float* __restrict__ pmP, const float* __restrict__ plP,
        int nsP, int Np, const float* __restrict__ residP, float* __restrict__ outP) {
    int idx = blockIdx.x * blockDim.x + threadIdx.x;
    const float *po, *pm, *pl, *resid;
    float* outc;
    int ns, Nq, i;
    int mtot = Nm * 64;
    if (idx < mtot) {
        po = poM; pm = pmM; pl = plM; ns = nsM; Nq = Nm; resid = residM; outc = outM; i = idx;
    } else {
        i = idx - mtot;
        if (i >= Np * 64) return;
        po = poP; pm = pmP; pl = plP; ns = nsP; Nq = Np; resid = residP; outc = outP;
    }
    int q = i >> 6, d = i & 63, h = d >> 4;
    float M = -1e30f;
    for (int s = 0; s < ns; ++s)
        M = fmaxf(M, pm[((size_t)s * Nq + q) * 4 + h]);
    float O = 0.f, L = 0.f;
    for (int s = 0; s < ns; ++s) {
        float wgt = fexp2(pm[((size_t)s * Nq + q) * 4 + h] - M);
        O += po[((size_t)s * Nq + q) * 64 + d] * wgt;
        L += pl[((size_t)s * Nq + q) * 4 + h] * wgt;
    }
    outc[i] = resid[i] + O / L;
}

// ---------------------------------------------------------------------------
// Per-batch pooling over sorted batch ranges: one block per (batch, graph).
// Direct stores, zero atomics.
// ---------------------------------------------------------------------------
__global__ __launch_bounds__(256) void k_pool2(
        const float* __restrict__ hM, const int* __restrict__ bsM,
        const float* __restrict__ hP, const int* __restrict__ bsP,
        float* __restrict__ zsum, float* __restrict__ zcnt) {
    __shared__ float red[4][64];
    int b = blockIdx.x & 63;
    int isP = blockIdx.x >> 6;
    const float* h = isP ? hP : hM;
    const int* bs = isP ? bsP : bsM;
    int colOff = isP ? 64 : 0;
    int n0 = bs[b], n1 = bs[b + 1];
    int w = threadIdx.x >> 6, c = threadIdx.x & 63;
    float acc = 0.f;
    for (int n = n0 + w; n < n1; n += 4)
        acc += h[(size_t)n * 64 + c];
    red[w][c] = acc;
    __syncthreads();
    if (w == 0) {
        float s = (red[0][c] + red[1][c]) + (red[2][c] + red[3][c]);
        zsum[b * 128 + colOff + c] = s;
        if (c == 0) zcnt[b * 2 + isP] = (float)(n1 - n0);
    }
}

// ---------------------------------------------------------------------------
// Head MLP: one wave per batch element
// ---------------------------------------------------------------------------
__global__ __launch_bounds__(256) void k_head2(
        const float* __restrict__ zsum, const float* __restrict__ zcnt,
        const float* __restrict__ fc1w, const float* __restrict__ fc1b,
        const float* __restrict__ fc2w, const float* __restrict__ fc2b,
        float* __restrict__ out) {
    int b = blockIdx.x * 4 + (threadIdx.x >> 6);
    int c = threadIdx.x & 63;
    float inv0 = 1.0f / fmaxf(zcnt[b * 2 + 0], 1.0f);
    float inv1 = 1.0f / fmaxf(zcnt[b * 2 + 1], 1.0f);
    float acc = fc1b[c];
    #pragma unroll 8
    for (int k = 0; k < 128; ++k) {
        float zv = zsum[b * 128 + k] * (k < 64 ? inv0 : inv1);
        acc += zv * fc1w[k * 64 + c];
    }
    float v = fmaxf(acc, 0.0f) * fc2w[c];
    #pragma unroll
    for (int off = 32; off > 0; off >>= 1) v += __shfl_xor(v, off);
    if (c == 0) out[b] = 1.0f / (1.0f + __expf(-(v + fc2b[0])));
}

// ---------------------------------------------------------------------------
extern "C" void kernel_launch(void* const* d_in, const int* in_sizes, int n_in,
                              void* d_out, int out_size, void* d_ws, size_t ws_size,
                              hipStream_t stream) {
    const float* x_mol  = (const float*)d_in[0];
    const float* x_prot = (const float*)d_in[1];
    const float* m1_wl = (const float*)d_in[2];
    const float* m1_bl = (const float*)d_in[3];
    const float* m1_wr = (const float*)d_in[4];
    const float* m2_wl = (const float*)d_in[5];
    const float* m2_bl = (const float*)d_in[6];
    const float* m2_wr = (const float*)d_in[7];
    const float* p1_wl = (const float*)d_in[8];
    const float* p1_bl = (const float*)d_in[9];
    const float* p1_wr = (const float*)d_in[10];
    const float* p2_wl = (const float*)d_in[11];
    const float* p2_bl = (const float*)d_in[12];
    const float* p2_wr = (const float*)d_in[13];
    const float* amp_w = (const float*)d_in[14];
    const float* amp_b = (const float*)d_in[15];
    const float* apm_w = (const float*)d_in[16];
    const float* apm_b = (const float*)d_in[17];
    const float* fc1_w = (const float*)d_in[18];
    const float* fc1_b = (const float*)d_in[19];
    const float* fc2_w = (const float*)d_in[20];
    const float* fc2_b = (const float*)d_in[21];
    const int* edge_mol  = (const int*)d_in[22];
    const int* edge_prot = (const int*)d_in[23];
    const int* batch_mol  = (const int*)d_in[24];
    const int* batch_prot = (const int*)d_in[25];
    float* out = (float*)d_out;

    const int N_MOL  = in_sizes[0] / 32;
    const int N_PROT = in_sizes[1] / 64;
    const int E_MOL  = in_sizes[22] / 2;
    const int E_PROT = in_sizes[23] / 2;

    // ---- workspace bump allocator ----
    char* base = (char*)d_ws;
    size_t off = 0;
    auto alloc = [&](size_t bytes) -> void* {
        void* p = base + off;
        off = (off + bytes + 255) & ~(size_t)255;
        return p;
    };
    float* h_mol1   = (float*)alloc((size_t)N_MOL * D * sizeof(float));
    float* h_mol2   = (float*)alloc((size_t)N_MOL * D * sizeof(float));
    float* h_prot1  = (float*)alloc((size_t)N_PROT * D * sizeof(float));
    float* h_prot2  = (float*)alloc((size_t)N_PROT * D * sizeof(float));
    float* h_mol_c  = (float*)alloc((size_t)N_MOL * D * sizeof(float));
    float* h_prot_c = (float*)alloc((size_t)N_PROT * D * sizeof(float));
    float* zsum     = (float*)alloc((NB * 128 + NB * 2) * sizeof(float));
    float* zcnt     = zsum + NB * 128;
    unsigned short* Qm_b = (unsigned short*)alloc((size_t)N_MOL * D * 2);
    unsigned short* Km_b = (unsigned short*)alloc((size_t)N_MOL * D * 2);
    unsigned short* Vm_b = (unsigned short*)alloc((size_t)N_MOL * D * 2);
    unsigned short* Vm_t = (unsigned short*)alloc((size_t)N_MOL * (D + 1) * 2);
    unsigned short* Qp_b = (unsigned short*)alloc((size_t)N_PROT * D * 2);
    unsigned short* Kp_b = (unsigned short*)alloc((size_t)N_PROT * D * 2);
    unsigned short* Vp_b = (unsigned short*)alloc((size_t)N_PROT * D * 2);
    unsigned short* Vp_t = (unsigned short*)alloc((size_t)N_PROT * (D + 1) * 2);
    // CSR
    int* deg      = (int*)alloc(((size_t)N_MOL + N_PROT) * sizeof(int));
    int* deg_m    = deg;
    int* deg_p    = deg + N_MOL;
    int* rp_m     = (int*)alloc(((size_t)N_MOL + 1) * sizeof(int));
    int* cur_m    = (int*)alloc((size_t)N_MOL * sizeof(int));
    int* csr_m    = (int*)alloc((size_t)E_MOL * sizeof(int));
    int* rp_p     = (int*)alloc(((size_t)N_PROT + 1) * sizeof(int));
    int* cur_p    = (int*)alloc((size_t)N_PROT * sizeof(int));
    int* csr_p    = (int*)alloc((size_t)E_PROT * sizeof(int));
    int* bsM      = (int*)alloc((NB + 1) * sizeof(int));
    int* bsP      = (int*)alloc((NB + 1) * sizeof(int));

    // split-K factors (keys per split must be a multiple of 64)
    int nsm = 16; while (nsm > 1 && (N_PROT % (64 * nsm))) nsm >>= 1;  // mol queries prot keys
    int nsp = 4;  while (nsp > 1 && (N_MOL % (64 * nsp)))  nsp >>= 1;  // prot queries mol keys
    int lsm = 31 - __builtin_clz(nsm);
    int lsp = 31 - __builtin_clz(nsp);
    float* poM = (float*)alloc((size_t)nsm * N_MOL * 64 * sizeof(float));
    float* pmM = (float*)alloc((size_t)nsm * N_MOL * 4 * sizeof(float));
    float* plM = (float*)alloc((size_t)nsm * N_MOL * 4 * sizeof(float));
    float* poP = (float*)alloc((size_t)nsp * N_PROT * 64 * sizeof(float));
    float* pmP = (float*)alloc((size_t)nsp * N_PROT * 4 * sizeof(float));
    float* plP = (float*)alloc((size_t)nsp * N_PROT * 4 * sizeof(float));

    const int BLK = 256;
    dim3 blk(BLK);
    const float QS = 0.25f * 1.4426950408889634f;  // 1/sqrt(DH) * log2(e)

    // ---- CSR build + batch starts ----
    hipMemsetAsync(deg, 0, ((size_t)N_MOL + N_PROT) * sizeof(int), stream);
    int Etot = E_MOL + E_PROT;
    k_prep2<<<(Etot + BLK - 1) / BLK, blk, 0, stream>>>(
        edge_mol, E_MOL, edge_prot, E_PROT, deg_m, deg_p,
        batch_mol, N_MOL, bsM, batch_prot, N_PROT, bsP);
    k_scan2<<<2, blk, 0, stream>>>(deg_m, N_MOL, rp_m, cur_m, deg_p, N_PROT, rp_p, cur_p);
    k_scatter2<<<(Etot + BLK - 1) / BLK, blk, 0, stream>>>(edge_mol, E_MOL, cur_m, csr_m,
                                                           edge_prot, E_PROT, cur_p, csr_p);

    // ---- SAGE layers (mol + prot merged per layer) ----
    k_gsage2<32, 64><<<N_MOL / 4 + N_PROT / 4, blk, 0, stream>>>(
        x_mol,  rp_m, csr_m, N_MOL,  m1_wl, m1_bl, m1_wr, h_mol1,
        x_prot, rp_p, csr_p, N_PROT, p1_wl, p1_bl, p1_wr, h_prot1);
    k_gsage2<64, 64><<<N_MOL / 4 + N_PROT / 4, blk, 0, stream>>>(
        h_mol1,  rp_m, csr_m, N_MOL,  m2_wl, m2_bl, m2_wr, h_mol2,
        h_prot1, rp_p, csr_p, N_PROT, p2_wl, p2_bl, p2_wr, h_prot2);

    // ---- QKV projections (merged) ----
    k_qkv2<<<N_MOL / 16 + N_PROT / 16, blk, 0, stream>>>(
        h_mol2, N_MOL, h_prot2, N_PROT, amp_w, amp_b, apm_w, apm_b, QS,
        Qm_b, Km_b, Vm_b, Qp_b, Kp_b, Vp_b);

    // ---- V transposes (merged, permuted, + ones row) ----
    k_transp2<<<N_MOL / 64 + N_PROT / 64, blk, 0, stream>>>(Vm_b, Vm_t, N_MOL, Vp_b, Vp_t, N_PROT);

    // ---- split-K flash attention (512-thread blocks, both directions) ----
    int gxm = (N_MOL / 64) * nsm;
    int gxp = (N_PROT / 64) * nsp;
    int gx = gxm > gxp ? gxm : gxp;
    k_attn6<<<dim3(gx, 2), dim3(512), 0, stream>>>(
        Qm_b, Kp_b, Vp_t, N_MOL, N_PROT, lsm, poM, pmM, plM,
        Qp_b, Km_b, Vm_t, lsp, poP, pmP, plP);

    // ---- combine + residual -> h_c (no atomics) ----
    if (nsm == 16 && nsp == 4) {
        int tot = (N_MOL + N_PROT) * 16;
        k_comb2t<16, 4><<<(tot + BLK - 1) / BLK, blk, 0, stream>>>(
            poM, pmM, plM, N_MOL, h_mol2, h_mol_c,
            poP, pmP, plP, N_PROT, h_prot2, h_prot_c);
    } else {
        k_comb2<<<((N_MOL + N_PROT) * 64 + BLK - 1) / BLK, blk, 0, stream>>>(
            poM, pmM, plM, nsm, N_MOL, h_mol2, h_mol_c,
            poP, pmP, plP, nsp, N_PROT, h_prot2, h_prot_c);
    }

    // ---- per-batch pooling (no atomics) ----
    k_pool2<<<128, blk, 0, stream>>>(h_mol_c, bsM, h_prot_c, bsP, zsum, zcnt);

    // ---- head ----
    k_head2<<<16, blk, 0, stream>>>(zsum, zcnt, fc1_w, fc1_b, fc2_w, fc2_b, out);
}

// Round 16
// 171.303 us; speedup vs baseline: 1.0356x; 1.0032x over previous
//
#include <hip/hip_runtime.h>
#include <math.h>

#define D 64
#define NB 64

typedef __attribute__((ext_vector_type(8))) short bf16x8;
typedef __attribute__((ext_vector_type(4))) float f32x4;
typedef __attribute__((ext_vector_type(16))) float f32x16;

#define M3(a, b, c) fmaxf(fmaxf((a), (b)), (c))

__device__ __forceinline__ unsigned short f2bf(float f) {
    unsigned u = __float_as_uint(f);
    u += 0x7FFF + ((u >> 16) & 1);
    return (unsigned short)(u >> 16);
}
__device__ __forceinline__ unsigned pk_bf16(float lo, float hi) {
    unsigned r;
    asm("v_cvt_pk_bf16_f32 %0, %1, %2" : "=v"(r) : "v"(lo), "v"(hi));
    return r;
}
__device__ __forceinline__ float fexp2(float x) {
    float r;
    asm("v_exp_f32 %0, %1" : "=v"(r) : "v"(x));
    return r;
}

// ---------------------------------------------------------------------------
// Prep: dst-degree histogram (both graphs) + batch start offsets (sorted ids)
// ---------------------------------------------------------------------------
__global__ void k_prep2(const int* __restrict__ em, int Em,
                        const int* __restrict__ ep, int Ep,
                        int* __restrict__ degm, int* __restrict__ degp,
                        const int* __restrict__ bm, int Nm, int* __restrict__ bsM,
                        const int* __restrict__ bp, int Np, int* __restrict__ bsP) {
    int i = blockIdx.x * blockDim.x + threadIdx.x;
    if (i < Em) atomicAdd(&degm[em[Em + i]], 1);
    int j = i - Em;
    if (j >= 0 && j < Ep) atomicAdd(&degp[ep[Ep + j]], 1);
    if (i < Nm) {
        int cur = bm[i];
        int prev = (i == 0) ? -1 : bm[i - 1];
        for (int b = prev + 1; b <= cur; ++b) bsM[b] = i;
        if (i == Nm - 1)
            for (int b = cur + 1; b <= NB; ++b) bsM[b] = Nm;
    }
    int j2 = i - Nm;
    if (j2 >= 0 && j2 < Np) {
        int cur = bp[j2];
        int prev = (j2 == 0) ? -1 : bp[j2 - 1];
        for (int b = prev + 1; b <= cur; ++b) bsP[b] = j2;
        if (j2 == Np - 1)
            for (int b = cur + 1; b <= NB; ++b) bsP[b] = Np;
    }
}

// ---------------------------------------------------------------------------
// CSR build: exclusive prefix sum (block 0 = mol, block 1 = prot)
// ---------------------------------------------------------------------------
__global__ __launch_bounds__(256) void k_scan2(
        const int* __restrict__ degm, int Nm, int* __restrict__ rpm, int* __restrict__ curm,
        const int* __restrict__ degp, int Np, int* __restrict__ rpp, int* __restrict__ curp) {
    __shared__ int sdeg[8192];
    __shared__ int chunk[256];
    const int* deg = blockIdx.x ? degp : degm;
    int N = blockIdx.x ? Np : Nm;
    int* rowptr = blockIdx.x ? rpp : rpm;
    int* cursor = blockIdx.x ? curp : curm;
    int t = threadIdx.x;
    for (int i = t; i < N; i += 256) sdeg[i] = deg[i];
    __syncthreads();
    int C = (N + 255) / 256;
    int start = t * C;
    int sum = 0;
    for (int i = 0; i < C; ++i)
        if (start + i < N) sum += sdeg[start + i];
    chunk[t] = sum;
    __syncthreads();
    for (int ofs = 1; ofs < 256; ofs <<= 1) {
        int v = (t >= ofs) ? chunk[t - ofs] : 0;
        __syncthreads();
        chunk[t] += v;
        __syncthreads();
    }
    int base = (t == 0) ? 0 : chunk[t - 1];
    for (int i = 0; i < C && start + i < N; ++i) {
        rowptr[start + i] = base;
        cursor[start + i] = base;
        base += sdeg[start + i];
    }
    if (t == 255) rowptr[N] = base;
}

// ---------------------------------------------------------------------------
// CSR build: scatter src indices (both graphs, one launch)
// ---------------------------------------------------------------------------
__global__ void k_scatter2(const int* __restrict__ em, int Em, int* __restrict__ curm,
                           int* __restrict__ csrm,
                           const int* __restrict__ ep, int Ep, int* __restrict__ curp,
                           int* __restrict__ csrp) {
    int i = blockIdx.x * blockDim.x + threadIdx.x;
    if (i < Em) {
        int s = em[i], d = em[Em + i];
        csrm[atomicAdd(&curm[d], 1)] = s;
    }
    int j = i - Em;
    if (j >= 0 && j < Ep) {
        int s = ep[j], d = ep[Ep + j];
        csrp[atomicAdd(&curp[d], 1)] = s;
    }
}

// ---------------------------------------------------------------------------
// Fused gather + SAGE linear, 16 rows/block (4 rows per wave, wave-local
// LDS slots so only the weight staging needs a barrier).
// ---------------------------------------------------------------------------
template<int FIN>
__device__ __forceinline__ void gsage3_body(
        const float* __restrict__ x, const int* __restrict__ rowptr,
        const int* __restrict__ csr, int N,
        const float* __restrict__ wl, const float* __restrict__ bl,
        const float* __restrict__ wr, float* __restrict__ out,
        int blk, float* __restrict__ swl, float* __restrict__ swr,
        float* __restrict__ sagg, float* __restrict__ sx) {
    for (int i = threadIdx.x; i < FIN * D; i += 256) { swl[i] = wl[i]; swr[i] = wr[i]; }
    __syncthreads();
    int w = threadIdx.x >> 6;
    int lane = threadIdx.x & 63;
    for (int rr = 0; rr < 4; ++rr) {
        int r = blk * 16 + w * 4 + rr;
        if (r >= N) return;
        int e0 = rowptr[r], e1 = rowptr[r + 1];
        float inv = 1.0f / fmaxf((float)(e1 - e0), 1.0f);
        if (FIN == 64) {
            float a0 = 0.f, a1 = 0.f, a2 = 0.f, a3 = 0.f;
            int e = e0;
            for (; e + 3 < e1; e += 4) {
                a0 += x[(size_t)csr[e] * FIN + lane];
                a1 += x[(size_t)csr[e + 1] * FIN + lane];
                a2 += x[(size_t)csr[e + 2] * FIN + lane];
                a3 += x[(size_t)csr[e + 3] * FIN + lane];
            }
            for (; e < e1; ++e) a0 += x[(size_t)csr[e] * FIN + lane];
            sagg[w * 64 + lane] = ((a0 + a1) + (a2 + a3)) * inv;
            sx[w * 64 + lane] = x[(size_t)r * FIN + lane];
        } else {
            int f = lane & 31, half = lane >> 5;
            float a = 0.f;
            for (int e = e0 + half; e < e1; e += 2)
                a += x[(size_t)csr[e] * FIN + f];
            a += __shfl_xor(a, 32);
            if (half == 0) {
                sagg[w * 64 + f] = a * inv;
                sx[w * 64 + f] = x[(size_t)r * FIN + f];
            }
        }
        int c = lane;
        float acc = bl[c];
        #pragma unroll 8
        for (int k = 0; k < FIN; ++k) {
            acc += sagg[w * 64 + k] * swl[k * D + c];
            acc += sx[w * 64 + k] * swr[k * D + c];
        }
        out[(size_t)r * D + c] = fmaxf(acc, 0.0f);
    }
}

template<int FA, int FB>
__global__ __launch_bounds__(256) void k_gsage3(
        const float* __restrict__ xA, const int* __restrict__ rpA,
        const int* __restrict__ csrA, int NA,
        const float* __restrict__ wlA, const float* __restrict__ blA,
        const float* __restrict__ wrA, float* __restrict__ outA,
        const float* __restrict__ xB, const int* __restrict__ rpB,
        const int* __restrict__ csrB, int NB_,
        const float* __restrict__ wlB, const float* __restrict__ blB,
        const float* __restrict__ wrB, float* __restrict__ outB) {
    __shared__ float swl[64 * 64];
    __shared__ float swr[64 * 64];
    __shared__ float sagg[4 * 64];
    __shared__ float sx[4 * 64];
    int bA = (NA + 15) / 16;
    if ((int)blockIdx.x < bA)
        gsage3_body<FA>(xA, rpA, csrA, NA, wlA, blA, wrA, outA, blockIdx.x, swl, swr, sagg, sx);
    else
        gsage3_body<FB>(xB, rpB, csrB, NB_, wlB, blB, wrB, outB, blockIdx.x - bA, swl, swr, sagg, sx);
}

// ---------------------------------------------------------------------------
// Fused QKV projection + permuted V transpose, 32 rows/block.
// Writes Q,K row-major bf16 (Q pre-scaled) and V directly into the
// transposed [65][N] layout (row 64 = ones; within-32-chunk permutation
// gmap={0,8,4,12} so attn's cvt_pk packing is the PV A-fragment).
// ---------------------------------------------------------------------------
__global__ __launch_bounds__(256) void k_qkv3(
        const float* __restrict__ xA, int NA, const float* __restrict__ xB, int NB_,
        const float* __restrict__ amp_w, const float* __restrict__ amp_b,
        const float* __restrict__ apm_w, const float* __restrict__ apm_b, float qs,
        unsigned short* __restrict__ QA, unsigned short* __restrict__ KA,
        unsigned short* __restrict__ VtA,
        unsigned short* __restrict__ QB, unsigned short* __restrict__ KB,
        unsigned short* __restrict__ VtB) {
    __shared__ float sq[D * D], sk[D * D], sv[D * D];
    __shared__ float sx[32 * D];
    __shared__ unsigned short svo[32][68];
    int bA = NA / 32;
    const float *x, *wq, *bq, *wk, *bk, *wv, *bv;
    unsigned short *oq, *ok, *vt;
    int blk, N;
    if ((int)blockIdx.x < bA) {
        x = xA; blk = blockIdx.x; N = NA;
        wq = amp_w;        bq = amp_b;
        wk = apm_w + 4096; bk = apm_b + 64;
        wv = apm_w + 8192; bv = apm_b + 128;
        oq = QA; ok = KA; vt = VtA;
    } else {
        x = xB; blk = blockIdx.x - bA; N = NB_;
        wq = apm_w;        bq = apm_b;
        wk = amp_w + 4096; bk = amp_b + 64;
        wv = amp_w + 8192; bv = amp_b + 128;
        oq = QB; ok = KB; vt = VtB;
    }
    for (int i = threadIdx.x; i < D * D; i += 256) { sq[i] = wq[i]; sk[i] = wk[i]; sv[i] = wv[i]; }
    int rbase = blk * 32;
    for (int i = threadIdx.x; i < 32 * D; i += 256) sx[i] = x[(size_t)rbase * D + i];
    __syncthreads();
    int c = threadIdx.x & 63;
    int r0 = (threadIdx.x >> 6) * 8;
    for (int rr = 0; rr < 8; ++rr) {
        int r = r0 + rr;
        float aq = bq[c], ak = bk[c], av = bv[c];
        #pragma unroll 8
        for (int k = 0; k < D; ++k) {
            float xv = sx[r * D + k];
            aq += xv * sq[k * D + c];
            ak += xv * sk[k * D + c];
            av += xv * sv[k * D + c];
        }
        size_t o = (size_t)(rbase + r) * D + c;
        oq[o] = f2bf(aq * qs);
        ok[o] = f2bf(ak);
        svo[r][c] = f2bf(av);
    }
    __syncthreads();
    // transposed V writes: 512 jobs = 64 cols x {b16 in 0,16} x {g in 0..3}
    const int gmap[4] = {0, 8, 4, 12};
    #pragma unroll
    for (int jj = 0; jj < 2; ++jj) {
        int j = threadIdx.x + jj * 256;
        int ccol = j & 63;
        int grp = j >> 6;           // 0..7
        int b16 = (grp & 4) ? 16 : 0;
        int g = grp & 3;
        int k0 = b16 + g * 4;
        union { uint2 v; unsigned short s[4]; } u;
        u.s[0] = svo[k0 + 0][ccol];
        u.s[1] = svo[k0 + 1][ccol];
        u.s[2] = svo[k0 + 2][ccol];
        u.s[3] = svo[k0 + 3][ccol];
        *(uint2*)(vt + (size_t)ccol * N + rbase + b16 + gmap[g]) = u.v;
    }
    if (threadIdx.x < 4) {
        uint4 ones;
        ones.x = ones.y = ones.z = ones.w = 0x3F803F80u;  // bf16 1.0 pairs
        *(uint4*)(vt + (size_t)64 * N + rbase + threadIdx.x * 8) = ones;
    }
}

// ---------------------------------------------------------------------------
// Split-K flash attention, 32x32x16 MFMA, 512-thread blocks (8 waves =
// 2 qtiles x 4 heads). 64-key iters, bias via MFMA C operand, deferred-max
// (T13), single accumulator, setprio around PV. Both directions one launch.
// ---------------------------------------------------------------------------
#define MAXTREE(cm, s0, s1)                                                   \
    {                                                                         \
        float c0 = M3(s0[0], s0[1], s0[2]);                                   \
        float c1 = M3(s0[3], s0[4], s0[5]);                                   \
        float c2 = M3(s0[6], s0[7], s0[8]);                                   \
        float c3 = M3(s0[9], s0[10], s0[11]);                                 \
        float c4 = M3(s0[12], s0[13], s0[14]);                                \
        float c5 = M3(s0[15], s1[0], s1[1]);                                  \
        float c6 = M3(s1[2], s1[3], s1[4]);                                   \
        float c7 = M3(s1[5], s1[6], s1[7]);                                   \
        float c8 = M3(s1[8], s1[9], s1[10]);                                  \
        float c9 = M3(s1[11], s1[12], s1[13]);                                \
        float ca = fmaxf(s1[14], s1[15]);                                     \
        float d0 = M3(c0, c1, c2);                                            \
        float d1 = M3(c3, c4, c5);                                            \
        float d2 = M3(c6, c7, c8);                                            \
        float d3 = M3(c9, ca, d0);                                            \
        cm = M3(d1, d2, d3);                                                  \
    }

#define PVPACK(S, KB)                                                         \
    {                                                                         \
        union { unsigned u[4]; bf16x8 v; } f1, f2;                            \
        f1.u[0] = pk_bf16((S)[0], (S)[1]);   f1.u[1] = pk_bf16((S)[2], (S)[3]);  \
        f1.u[2] = pk_bf16((S)[4], (S)[5]);   f1.u[3] = pk_bf16((S)[6], (S)[7]);  \
        f2.u[0] = pk_bf16((S)[8], (S)[9]);   f2.u[1] = pk_bf16((S)[10], (S)[11]);\
        f2.u[2] = pk_bf16((S)[12], (S)[13]); f2.u[3] = pk_bf16((S)[14], (S)[15]);\
        bf16x8 vb0 = *(const bf16x8*)(vbase + (KB) + half * 8);               \
        bf16x8 vb1 = *(const bf16x8*)(vbase + (KB) + 16 + half * 8);          \
        __builtin_amdgcn_s_setprio(1);                                        \
        o = __builtin_amdgcn_mfma_f32_32x32x16_bf16(f1.v, vb0, o, 0, 0, 0);   \
        o = __builtin_amdgcn_mfma_f32_32x32x16_bf16(f2.v, vb1, o, 0, 0, 0);   \
        __builtin_amdgcn_s_setprio(0);                                        \
    }

__global__ __launch_bounds__(512) void k_attn6(
        const unsigned short* __restrict__ QmB, const unsigned short* __restrict__ KpB,
        const unsigned short* __restrict__ VpT, int Nm, int Np, int lsm,
        float* __restrict__ poM, float* __restrict__ pmM, float* __restrict__ plM,
        const unsigned short* __restrict__ QpB, const unsigned short* __restrict__ KmB,
        const unsigned short* __restrict__ VmT, int lsp,
        float* __restrict__ poP, float* __restrict__ pmP, float* __restrict__ plP) {
    const unsigned short *Q, *K, *Vt;
    int Nq, Nk, ls;
    float *po, *pm, *pl;
    if (blockIdx.y == 0) { Q = QmB; K = KpB; Vt = VpT; Nq = Nm; Nk = Np; ls = lsm; po = poM; pm = pmM; pl = plM; }
    else                 { Q = QpB; K = KmB; Vt = VmT; Nq = Np; Nk = Nm; ls = lsp; po = poP; pm = pmP; pl = plP; }
    int npair = Nq >> 6;
    if ((int)blockIdx.x >= (npair << ls)) return;
    const int qpair = blockIdx.x >> ls;
    const int split = blockIdx.x & ((1 << ls) - 1);
    const int kchunk = Nk >> ls;
    const int w = threadIdx.x >> 6;
    const int h = w & 3;
    const int qt = qpair * 2 + (w >> 2);
    const int lane = threadIdx.x & 63;
    const int cq = lane & 31;
    const int half = lane >> 5;
    const int h16 = h * 16;

    bf16x8 qb = *(const bf16x8*)(Q + ((size_t)(qt * 32 + cq) * D + h16 + half * 8));
    int drow = (cq < 16) ? (h16 + cq) : (cq == 16 ? 64 : h16 + 15);
    const unsigned short* vbase = Vt + (size_t)drow * Nk;

    f32x16 o, mC;
    #pragma unroll
    for (int i = 0; i < 16; ++i) { o[i] = 0.f; mC[i] = 0.f; }
    float m;

    const int kstart = split * kchunk;
    {
        const int kb = kstart;
        bf16x8 ka0 = *(const bf16x8*)(K + ((size_t)(kb + cq) * D + h16 + half * 8));
        bf16x8 ka1 = *(const bf16x8*)(K + ((size_t)(kb + 32 + cq) * D + h16 + half * 8));
        f32x16 s0 = __builtin_amdgcn_mfma_f32_32x32x16_bf16(ka0, qb, mC, 0, 0, 0);
        f32x16 s1 = __builtin_amdgcn_mfma_f32_32x32x16_bf16(ka1, qb, mC, 0, 0, 0);
        float cm;
        MAXTREE(cm, s0, s1);
        #pragma unroll
        for (int off = 1; off < 64; off <<= 1) cm = fmaxf(cm, __shfl_xor(cm, off));
        m = cm;
        #pragma unroll
        for (int i = 0; i < 16; ++i) {
            s0[i] = fexp2(s0[i] - m);
            s1[i] = fexp2(s1[i] - m);
            mC[i] = -m;
        }
        PVPACK(s0, kb)
        PVPACK(s1, kb + 32)
    }
    for (int kb = kstart + 64; kb < kstart + kchunk; kb += 64) {
        bf16x8 ka0 = *(const bf16x8*)(K + ((size_t)(kb + cq) * D + h16 + half * 8));
        bf16x8 ka1 = *(const bf16x8*)(K + ((size_t)(kb + 32 + cq) * D + h16 + half * 8));
        f32x16 s0 = __builtin_amdgcn_mfma_f32_32x32x16_bf16(ka0, qb, mC, 0, 0, 0);
        f32x16 s1 = __builtin_amdgcn_mfma_f32_32x32x16_bf16(ka1, qb, mC, 0, 0, 0);
        float cm;
        MAXTREE(cm, s0, s1);
        if (__any(cm > 8.f)) {            // deferred-max rescale (T13)
            float cw = cm;
            #pragma unroll
            for (int off = 1; off < 64; off <<= 1) cw = fmaxf(cw, __shfl_xor(cw, off));
            float nm = fmaxf(m + cw, m);
            float sc = fexp2(m - nm);
            #pragma unroll
            for (int i = 0; i < 16; ++i) o[i] *= sc;
            float dl = nm - m;
            #pragma unroll
            for (int i = 0; i < 16; ++i) { s0[i] -= dl; s1[i] -= dl; mC[i] = -nm; }
            m = nm;
        }
        #pragma unroll
        for (int i = 0; i < 16; ++i) { s0[i] = fexp2(s0[i]); s1[i] = fexp2(s1[i]); }
        PVPACK(s0, kb)
        PVPACK(s1, kb + 32)
    }

    size_t pbase = (size_t)split * Nq + qt * 32;
    if (half == 0)
        pm[(pbase + cq) * 4 + h] = m;
    if (cq == 16) {
        #pragma unroll
        for (int r = 0; r < 16; ++r) {
            int qr = (r & 3) + 8 * (r >> 2) + 4 * half;
            pl[(pbase + qr) * 4 + h] = o[r];
        }
    }
    if (cq < 16) {
        #pragma unroll
        for (int r = 0; r < 16; ++r) {
            int qr = (r & 3) + 8 * (r >> 2) + 4 * half;
            po[(pbase + qr) * 64 + h16 + cq] = o[r];
        }
    }
}

// ---------------------------------------------------------------------------
// Combine split-K partials + residual -> dense h_c (no atomics)
// ---------------------------------------------------------------------------
template<int NS>
__device__ __forceinline__ void comb_body(
        const float* __restrict__ po, const float* __restrict__ pm,
        const float* __restrict__ pl, int Nq,
        const float* __restrict__ resid, float* __restrict__ outc, int i) {
    int q = i >> 4;
    int part = i & 15;
    int d0 = part * 4;
    int h = part >> 2;
    float pmv[NS], plv[NS];
    #pragma unroll
    for (int s = 0; s < NS; ++s) pmv[s] = pm[((size_t)s * Nq + q) * 4 + h];
    #pragma unroll
    for (int s = 0; s < NS; ++s) plv[s] = pl[((size_t)s * Nq + q) * 4 + h];
    float M = pmv[0];
    #pragma unroll
    for (int s = 1; s < NS; ++s) M = fmaxf(M, pmv[s]);
    float4 O = {0.f, 0.f, 0.f, 0.f};
    float L = 0.f;
    #pragma unroll
    for (int s = 0; s < NS; ++s) {
        float wgt = fexp2(pmv[s] - M);
        float4 pv = *(const float4*)(po + ((size_t)s * Nq + q) * 64 + d0);
        O.x += pv.x * wgt; O.y += pv.y * wgt; O.z += pv.z * wgt; O.w += pv.w * wgt;
        L += plv[s] * wgt;
    }
    float invL = 1.0f / L;
    float4 rv = *(const float4*)(resid + (size_t)q * 64 + d0);
    float4 res;
    res.x = rv.x + O.x * invL;
    res.y = rv.y + O.y * invL;
    res.z = rv.z + O.z * invL;
    res.w = rv.w + O.w * invL;
    *(float4*)(outc + (size_t)q * 64 + d0) = res;
}

template<int NSM, int NSP>
__global__ void k_comb2t(
        const float* __restrict__ poM, const float* __restrict__ pmM, const float* __restrict__ plM,
        int Nm, const float* __restrict__ residM, float* __restrict__ outM,
        const float* __restrict__ poP, const float* __restrict__ pmP, const float* __restrict__ plP,
        int Np, const float* __restrict__ residP, float* __restrict__ outP) {
    int idx = blockIdx.x * blockDim.x + threadIdx.x;
    int mtot = Nm * 16;
    if (idx < mtot)
        comb_body<NSM>(poM, pmM, plM, Nm, residM, outM, idx);
    else if (idx - mtot < Np * 16)
        comb_body<NSP>(poP, pmP, plP, Np, residP, outP, idx - mtot);
}

// Generic fallback (runtime ns)
__global__ void k_comb2(
        const float* __restrict__ poM, const float* __restrict__ pmM, const float* __restrict__ plM,
        int nsM, int Nm, const float* __restrict__ residM, float* __restrict__ outM,
        const float* __restrict__ poP, const float* __restrict__ pmP, const float* __restrict__ plP,
        int nsP, int Np, const float* __restrict__ residP, float* __restrict__ outP) {
    int idx = blockIdx.x * blockDim.x + threadIdx.x;
    const float *po, *pm, *pl, *resid;
    float* outc;
    int ns, Nq, i;
    int mtot = Nm * 64;
    if (idx < mtot) {
        po = poM; pm = pmM; pl = plM; ns = nsM; Nq = Nm; resid = residM; outc = outM; i = idx;
    } else {
        i = idx - mtot;
        if (i >= Np * 64) return;
        po = poP; pm = pmP; pl = plP; ns = nsP; Nq = Np; resid = residP; outc = outP;
    }
    int q = i >> 6, d = i & 63, h = d >> 4;
    float M = -1e30f;
    for (int s = 0; s < ns; ++s)
        M = fmaxf(M, pm[((size_t)s * Nq + q) * 4 + h]);
    float O = 0.f, L = 0.f;
    for (int s = 0; s < ns; ++s) {
        float wgt = fexp2(pm[((size_t)s * Nq + q) * 4 + h] - M);
        O += po[((size_t)s * Nq + q) * 64 + d] * wgt;
        L += pl[((size_t)s * Nq + q) * 4 + h] * wgt;
    }
    outc[i] = resid[i] + O / L;
}

// ---------------------------------------------------------------------------
// Fused per-batch pooling + head MLP: one block per batch element.
// ---------------------------------------------------------------------------
__global__ __launch_bounds__(256) void k_poolhead(
        const float* __restrict__ hM, const int* __restrict__ bsM,
        const float* __restrict__ hP, const int* __restrict__ bsP,
        const float* __restrict__ fc1w, const float* __restrict__ fc1b,
        const float* __restrict__ fc2w, const float* __restrict__ fc2b,
        float* __restrict__ out) {
    __shared__ float red[4][64];
    __shared__ float zs[128];
    int b = blockIdx.x;
    int w = threadIdx.x >> 6, c = threadIdx.x & 63;
    // mol half
    int n0 = bsM[b], n1 = bsM[b + 1];
    float acc = 0.f;
    for (int n = n0 + w; n < n1; n += 4) acc += hM[(size_t)n * 64 + c];
    red[w][c] = acc;
    __syncthreads();
    if (w == 0)
        zs[c] = ((red[0][c] + red[1][c]) + (red[2][c] + red[3][c])) /
                fmaxf((float)(n1 - n0), 1.0f);
    __syncthreads();
    // prot half
    n0 = bsP[b]; n1 = bsP[b + 1];
    acc = 0.f;
    for (int n = n0 + w; n < n1; n += 4) acc += hP[(size_t)n * 64 + c];
    red[w][c] = acc;
    __syncthreads();
    if (w == 0)
        zs[64 + c] = ((red[0][c] + red[1][c]) + (red[2][c] + red[3][c])) /
                     fmaxf((float)(n1 - n0), 1.0f);
    __syncthreads();
    // head (wave 0)
    if (w == 0) {
        float a = fc1b[c];
        #pragma unroll 8
        for (int k = 0; k < 128; ++k) a += zs[k] * fc1w[k * 64 + c];
        float v = fmaxf(a, 0.0f) * fc2w[c];
        #pragma unroll
        for (int off = 32; off > 0; off >>= 1) v += __shfl_xor(v, off);
        if (c == 0) out[b] = 1.0f / (1.0f + __expf(-(v + fc2b[0])));
    }
}

// ---------------------------------------------------------------------------
extern "C" void kernel_launch(void* const* d_in, const int* in_sizes, int n_in,
                              void* d_out, int out_size, void* d_ws, size_t ws_size,
                              hipStream_t stream) {
    const float* x_mol  = (const float*)d_in[0];
    const float* x_prot = (const float*)d_in[1];
    const float* m1_wl = (const float*)d_in[2];
    const float* m1_bl = (const float*)d_in[3];
    const float* m1_wr = (const float*)d_in[4];
    const float* m2_wl = (const float*)d_in[5];
    const float* m2_bl = (const float*)d_in[6];
    const float* m2_wr = (const float*)d_in[7];
    const float* p1_wl = (const float*)d_in[8];
    const float* p1_bl = (const float*)d_in[9];
    const float* p1_wr = (const float*)d_in[10];
    const float* p2_wl = (const float*)d_in[11];
    const float* p2_bl = (const float*)d_in[12];
    const float* p2_wr = (const float*)d_in[13];
    const float* amp_w = (const float*)d_in[14];
    const float* amp_b = (const float*)d_in[15];
    const float* apm_w = (const float*)d_in[16];
    const float* apm_b = (const float*)d_in[17];
    const float* fc1_w = (const float*)d_in[18];
    const float* fc1_b = (const float*)d_in[19];
    const float* fc2_w = (const float*)d_in[20];
    const float* fc2_b = (const float*)d_in[21];
    const int* edge_mol  = (const int*)d_in[22];
    const int* edge_prot = (const int*)d_in[23];
    const int* batch_mol  = (const int*)d_in[24];
    const int* batch_prot = (const int*)d_in[25];
    float* out = (float*)d_out;

    const int N_MOL  = in_sizes[0] / 32;
    const int N_PROT = in_sizes[1] / 64;
    const int E_MOL  = in_sizes[22] / 2;
    const int E_PROT = in_sizes[23] / 2;

    // ---- workspace bump allocator ----
    char* base = (char*)d_ws;
    size_t off = 0;
    auto alloc = [&](size_t bytes) -> void* {
        void* p = base + off;
        off = (off + bytes + 255) & ~(size_t)255;
        return p;
    };
    float* h_mol1   = (float*)alloc((size_t)N_MOL * D * sizeof(float));
    float* h_mol2   = (float*)alloc((size_t)N_MOL * D * sizeof(float));
    float* h_prot1  = (float*)alloc((size_t)N_PROT * D * sizeof(float));
    float* h_prot2  = (float*)alloc((size_t)N_PROT * D * sizeof(float));
    float* h_mol_c  = (float*)alloc((size_t)N_MOL * D * sizeof(float));
    float* h_prot_c = (float*)alloc((size_t)N_PROT * D * sizeof(float));
    unsigned short* Qm_b = (unsigned short*)alloc((size_t)N_MOL * D * 2);
    unsigned short* Km_b = (unsigned short*)alloc((size_t)N_MOL * D * 2);
    unsigned short* Vm_t = (unsigned short*)alloc((size_t)N_MOL * (D + 1) * 2);
    unsigned short* Qp_b = (unsigned short*)alloc((size_t)N_PROT * D * 2);
    unsigned short* Kp_b = (unsigned short*)alloc((size_t)N_PROT * D * 2);
    unsigned short* Vp_t = (unsigned short*)alloc((size_t)N_PROT * (D + 1) * 2);
    // CSR
    int* deg      = (int*)alloc(((size_t)N_MOL + N_PROT) * sizeof(int));
    int* deg_m    = deg;
    int* deg_p    = deg + N_MOL;
    int* rp_m     = (int*)alloc(((size_t)N_MOL + 1) * sizeof(int));
    int* cur_m    = (int*)alloc((size_t)N_MOL * sizeof(int));
    int* csr_m    = (int*)alloc((size_t)E_MOL * sizeof(int));
    int* rp_p     = (int*)alloc(((size_t)N_PROT + 1) * sizeof(int));
    int* cur_p    = (int*)alloc((size_t)N_PROT * sizeof(int));
    int* csr_p    = (int*)alloc((size_t)E_PROT * sizeof(int));
    int* bsM      = (int*)alloc((NB + 1) * sizeof(int));
    int* bsP      = (int*)alloc((NB + 1) * sizeof(int));

    // split-K factors (keys per split must be a multiple of 64)
    int nsm = 16; while (nsm > 1 && (N_PROT % (64 * nsm))) nsm >>= 1;
    int nsp = 4;  while (nsp > 1 && (N_MOL % (64 * nsp)))  nsp >>= 1;
    int lsm = 31 - __builtin_clz(nsm);
    int lsp = 31 - __builtin_clz(nsp);
    float* poM = (float*)alloc((size_t)nsm * N_MOL * 64 * sizeof(float));
    float* pmM = (float*)alloc((size_t)nsm * N_MOL * 4 * sizeof(float));
    float* plM = (float*)alloc((size_t)nsm * N_MOL * 4 * sizeof(float));
    float* poP = (float*)alloc((size_t)nsp * N_PROT * 64 * sizeof(float));
    float* pmP = (float*)alloc((size_t)nsp * N_PROT * 4 * sizeof(float));
    float* plP = (float*)alloc((size_t)nsp * N_PROT * 4 * sizeof(float));

    const int BLK = 256;
    dim3 blk(BLK);
    const float QS = 0.25f * 1.4426950408889634f;  // 1/sqrt(DH) * log2(e)

    // ---- CSR build + batch starts ----
    hipMemsetAsync(deg, 0, ((size_t)N_MOL + N_PROT) * sizeof(int), stream);
    int Etot = E_MOL + E_PROT;
    k_prep2<<<(Etot + BLK - 1) / BLK, blk, 0, stream>>>(
        edge_mol, E_MOL, edge_prot, E_PROT, deg_m, deg_p,
        batch_mol, N_MOL, bsM, batch_prot, N_PROT, bsP);
    k_scan2<<<2, blk, 0, stream>>>(deg_m, N_MOL, rp_m, cur_m, deg_p, N_PROT, rp_p, cur_p);
    k_scatter2<<<(Etot + BLK - 1) / BLK, blk, 0, stream>>>(edge_mol, E_MOL, cur_m, csr_m,
                                                           edge_prot, E_PROT, cur_p, csr_p);

    // ---- SAGE layers (16 rows/block, mol + prot merged per layer) ----
    int gs = (N_MOL + 15) / 16 + (N_PROT + 15) / 16;
    k_gsage3<32, 64><<<gs, blk, 0, stream>>>(
        x_mol,  rp_m, csr_m, N_MOL,  m1_wl, m1_bl, m1_wr, h_mol1,
        x_prot, rp_p, csr_p, N_PROT, p1_wl, p1_bl, p1_wr, h_prot1);
    k_gsage3<64, 64><<<gs, blk, 0, stream>>>(
        h_mol1,  rp_m, csr_m, N_MOL,  m2_wl, m2_bl, m2_wr, h_mol2,
        h_prot1, rp_p, csr_p, N_PROT, p2_wl, p2_bl, p2_wr, h_prot2);

    // ---- QKV projections + fused V transpose (merged) ----
    k_qkv3<<<N_MOL / 32 + N_PROT / 32, blk, 0, stream>>>(
        h_mol2, N_MOL, h_prot2, N_PROT, amp_w, amp_b, apm_w, apm_b, QS,
        Qm_b, Km_b, Vm_t, Qp_b, Kp_b, Vp_t);

    // ---- split-K flash attention (512-thread blocks, both directions) ----
    int gxm = (N_MOL / 64) * nsm;
    int gxp = (N_PROT / 64) * nsp;
    int gx = gxm > gxp ? gxm : gxp;
    k_attn6<<<dim3(gx, 2), dim3(512), 0, stream>>>(
        Qm_b, Kp_b, Vp_t, N_MOL, N_PROT, lsm, poM, pmM, plM,
        Qp_b, Km_b, Vm_t, lsp, poP, pmP, plP);

    // ---- combine + residual -> h_c (no atomics) ----
    if (nsm == 16 && nsp == 4) {
        int tot = (N_MOL + N_PROT) * 16;
        k_comb2t<16, 4><<<(tot + BLK - 1) / BLK, blk, 0, stream>>>(
            poM, pmM, plM, N_MOL, h_mol2, h_mol_c,
            poP, pmP, plP, N_PROT, h_prot2, h_prot_c);
    } else {
        k_comb2<<<((N_MOL + N_PROT) * 64 + BLK - 1) / BLK, blk, 0, stream>>>(
            poM, pmM, plM, nsm, N_MOL, h_mol2, h_mol_c,
            poP, pmP, plP, nsp, N_PROT, h_prot2, h_prot_c);
    }

    // ---- fused pooling + head ----
    k_poolhead<<<NB, blk, 0, stream>>>(h_mol_c, bsM, h_prot_c, bsP,
                                       fc1_w, fc1_b, fc2_w, fc2_b, out);
}